// Round 9
// baseline (190.657 us; speedup 1.0000x reference)
//
#include <hip/hip_runtime.h>
#include <math.h>

#define BATCH 2
#define SEQ   2048
#define DMODEL 1024
#define NHEAD 16
#define HEADD 64
#define MROWS 4096

typedef __attribute__((ext_vector_type(8))) __bf16 bf16x8;
typedef __attribute__((ext_vector_type(4))) float f32x4;

__device__ __forceinline__ ushort f2bf(float f) {
    uint u = __float_as_uint(f);
    u += 0x7fffu + ((u >> 16) & 1u);
    return (ushort)(u >> 16);
}
__device__ __forceinline__ float bf2f(ushort h) {
    return __uint_as_float(((uint)h) << 16);
}
__device__ __forceinline__ ushort4 pack4bf(float a, float b, float c, float d) {
    union { __bf16 h[4]; ushort4 u; } p;
    p.h[0] = (__bf16)a; p.h[1] = (__bf16)b; p.h[2] = (__bf16)c; p.h[3] = (__bf16)d;
    return p.u;
}
__device__ __forceinline__ float vmax4(const f32x4 v) {
    return fmaxf(fmaxf(v[0], v[1]), fmaxf(v[2], v[3]));
}

#define GLD16(gsrc, ldst)                                                         \
    __builtin_amdgcn_global_load_lds(                                             \
        (const __attribute__((address_space(1))) unsigned int*)(gsrc),            \
        (__attribute__((address_space(3))) unsigned int*)(ldst), 16, 0, 0)

// Q pre-scale: (1/sqrt(64)) * log2(e)  -> softmax in exp2 domain
#define QSCALE 0.1803368801111204f

// ---------------- prep: x fp32 -> bf16 (hi only) ----------------
__global__ __launch_bounds__(256) void split_x(const float* __restrict__ in,
                                               ushort* __restrict__ oh, int n4) {
    int i = blockIdx.x * 256 + threadIdx.x;
    const int stride = gridDim.x * 256;
    for (; i < n4; i += stride) {
        const float4 v = reinterpret_cast<const float4*>(in)[i];
        ushort4 h;
        h.x = f2bf(v.x); h.y = f2bf(v.y); h.z = f2bf(v.z); h.w = f2bf(v.w);
        reinterpret_cast<ushort4*>(oh)[i] = h;
    }
}

// ---------------- prep: W^T; z<3 -> combined QKV hi; z==3 -> Wo hi/lo ----------------
__global__ __launch_bounds__(256) void tsplit_w(const float* __restrict__ Wq,
                                                const float* __restrict__ Wk,
                                                const float* __restrict__ Wv,
                                                const float* __restrict__ Wo,
                                                ushort* __restrict__ wtc,
                                                ushort* __restrict__ woh,
                                                ushort* __restrict__ wol) {
    const int z = blockIdx.z;
    const float* W = (z == 0) ? Wq : (z == 1) ? Wk : (z == 2) ? Wv : Wo;
    __shared__ float T[64][68];
    const int t = threadIdx.x;
    const int k0 = blockIdx.y * 64, n0 = blockIdx.x * 64;
    {
        const int r = t >> 2, c0 = (t & 3) * 16;
        #pragma unroll
        for (int j = 0; j < 4; ++j)
            *reinterpret_cast<float4*>(&T[r][c0 + j * 4]) =
                *reinterpret_cast<const float4*>(&W[(size_t)(k0 + r) * DMODEL + n0 + c0 + j * 4]);
    }
    __syncthreads();
    const int nl = t >> 2, kq = t & 3;
    if (z < 3) {
        ushort hb[16];
        #pragma unroll
        for (int e = 0; e < 16; ++e) hb[e] = f2bf(T[kq * 16 + e][nl]);
        const size_t o = (size_t)(z * 1024 + n0 + nl) * DMODEL + k0 + kq * 16;
        *reinterpret_cast<uint4*>(&wtc[o]) = *reinterpret_cast<uint4*>(&hb[0]);
        *reinterpret_cast<uint4*>(&wtc[o + 8]) = *reinterpret_cast<uint4*>(&hb[8]);
    } else {
        ushort hb[16], lb[16];
        #pragma unroll
        for (int e = 0; e < 16; ++e) {
            const float v = T[kq * 16 + e][nl];
            const ushort h = f2bf(v);
            hb[e] = h; lb[e] = f2bf(v - bf2f(h));
        }
        const size_t o = (size_t)(n0 + nl) * DMODEL + k0 + kq * 16;
        *reinterpret_cast<uint4*>(&woh[o]) = *reinterpret_cast<uint4*>(&hb[0]);
        *reinterpret_cast<uint4*>(&woh[o + 8]) = *reinterpret_cast<uint4*>(&hb[8]);
        *reinterpret_cast<uint4*>(&wol[o]) = *reinterpret_cast<uint4*>(&lb[0]);
        *reinterpret_cast<uint4*>(&wol[o + 8]) = *reinterpret_cast<uint4*>(&lb[8]);
    }
}

// ---------------- fused QKV GEMM: single-pass bf16, 128x128 tile, BK=64 ----------------
__global__ __launch_bounds__(512) void gemm_qkv(const ushort* __restrict__ xh,
                                                const ushort* __restrict__ wtc,
                                                ushort* __restrict__ Qb,
                                                ushort* __restrict__ Kb,
                                                ushort* __restrict__ Vtb) {
    __shared__ ushort SH[17408];
    ushort* const Ah = SH;
    ushort* const Bh = SH + 8192;

    const int t = threadIdx.x, lane = t & 63, w = t >> 6;
    const int l = lane & 15, g = lane >> 4;
    const int wm = w >> 2, wn = w & 3;
    const int bm = blockIdx.y * 128, bn = blockIdx.x * 128;

    f32x4 acc[4][2];
    #pragma unroll
    for (int mt = 0; mt < 4; ++mt)
        #pragma unroll
        for (int nt = 0; nt < 2; ++nt) acc[mt][nt] = (f32x4){0.f, 0.f, 0.f, 0.f};

    for (int kt = 0; kt < DMODEL; kt += 64) {
        __syncthreads();
        #pragma unroll
        for (int i = 0; i < 4; ++i) {
            const int sid = w * 4 + i;
            const int c = sid & 15;
            const ushort* src = (sid < 16) ? xh : wtc;
            const int rb = (sid < 16) ? bm : bn;
            ushort* dst = ((sid < 16) ? Ah : Bh) + c * 512;
            const int row = c * 8 + (lane >> 3);
            const int sw = ((lane & 7) ^ (row & 7)) << 3;
            GLD16(src + (size_t)(rb + row) * DMODEL + kt + sw, dst);
        }
        __syncthreads();

        bf16x8 af[4][2], bf[2][2];
        #pragma unroll
        for (int mt = 0; mt < 4; ++mt)
            #pragma unroll
            for (int s = 0; s < 2; ++s) {
                const int m = wm * 64 + mt * 16 + l;
                af[mt][s] = *reinterpret_cast<const bf16x8*>(&Ah[m * 64 + (((g + 4 * s) ^ (m & 7)) << 3)]);
            }
        #pragma unroll
        for (int nt = 0; nt < 2; ++nt)
            #pragma unroll
            for (int s = 0; s < 2; ++s) {
                const int n = wn * 32 + nt * 16 + l;
                bf[nt][s] = *reinterpret_cast<const bf16x8*>(&Bh[n * 64 + (((g + 4 * s) ^ (n & 7)) << 3)]);
            }
        #pragma unroll
        for (int mt = 0; mt < 4; ++mt)
            #pragma unroll
            for (int nt = 0; nt < 2; ++nt)
                #pragma unroll
                for (int s = 0; s < 2; ++s)
                    acc[mt][nt] = __builtin_amdgcn_mfma_f32_16x16x32_bf16(af[mt][s], bf[nt][s], acc[mt][nt], 0, 0, 0);
    }

    const int mode = bn >> 10;
    if (mode == 0) {
        #pragma unroll
        for (int mt = 0; mt < 4; ++mt)
            #pragma unroll
            for (int nt = 0; nt < 2; ++nt)
                #pragma unroll
                for (int r = 0; r < 4; ++r) {
                    const int row = bm + wm * 64 + mt * 16 + g * 4 + r;
                    const int col = bn + wn * 32 + nt * 16 + l;
                    Qb[(size_t)row * DMODEL + col] = f2bf(acc[mt][nt][r] * QSCALE);
                }
    } else if (mode == 1) {
        #pragma unroll
        for (int mt = 0; mt < 4; ++mt)
            #pragma unroll
            for (int nt = 0; nt < 2; ++nt)
                #pragma unroll
                for (int r = 0; r < 4; ++r) {
                    const int row = bm + wm * 64 + mt * 16 + g * 4 + r;
                    const int col = (bn - 1024) + wn * 32 + nt * 16 + l;
                    Kb[(size_t)row * DMODEL + col] = f2bf(acc[mt][nt][r]);
                }
    } else {
        __syncthreads();
        ushort* VtL = SH;   // [128 d][136 key]
        #pragma unroll
        for (int mt = 0; mt < 4; ++mt)
            #pragma unroll
            for (int nt = 0; nt < 2; ++nt)
                #pragma unroll
                for (int r = 0; r < 4; ++r) {
                    const int dl = wn * 32 + nt * 16 + l;
                    const int kl = wm * 64 + mt * 16 + g * 4 + r;
                    VtL[dl * 136 + kl] = f2bf(acc[mt][nt][r]);
                }
        __syncthreads();
        const int dl = t >> 2, kq = t & 3;
        const int b = bm >> 11;
        const int row = b * 1024 + (bn - 2048) + dl;
        const int key0 = bm & 2047;
        const size_t o = (size_t)row * SEQ + key0 + kq * 32;
        #pragma unroll
        for (int j = 0; j < 4; ++j)
            *reinterpret_cast<uint4*>(&Vtb[o + j * 8]) =
                *reinterpret_cast<uint4*>(&VtL[dl * 136 + kq * 32 + j * 8]);
    }
}

// ---------------- attention: paired tiles, explicit 2-deep register pipeline ----------------
// Grid (x=bh 32, y=pair 16): XCD-local bh -> K/V L2-resident. Block = 256 thr (4 waves);
// wave w owns 16 rows of tile pair (set 0) + 16 rows of tile 31-pair (set 1).
// kf0/vf0 and kf1/vf1 alternate: loads for chunk i+1 are issued before computing
// chunk i and stay live across it -> compiler cannot sink the prefetch.
#define LDP 72

__global__ __launch_bounds__(256, 2) void attn(const ushort* __restrict__ Q,
                                               const ushort* __restrict__ K,
                                               const ushort* __restrict__ Vt,
                                               ushort* __restrict__ ATh,
                                               ushort* __restrict__ ATl) {
    __shared__ ushort Pl[128 * LDP];   // wave-private rows

    const int t = threadIdx.x, lane = t & 63, w = t >> 6;
    const int l = lane & 15, g = lane >> 4;
    const int pair = blockIdx.y;                  // 0..15
    const int tA = pair, tB = 31 - pair;
    const int bh = blockIdx.x, b = bh >> 4, h = bh & 15;
    const size_t kbase = (size_t)b * SEQ * DMODEL + h * 64;
    const size_t vbase = (size_t)bh * 64 * SEQ;
    const int qrow0[2] = {tA * 64 + w * 16, tB * 64 + w * 16};
    const int nchA = tA + 1, nchB = tB + 1;       // nchA <= 16 < nchB

    // Q B-operand frags (col=q=lane&15, k=d=32s+8g+e)
    bf16x8 qf[2][2];
    #pragma unroll
    for (int qs = 0; qs < 2; ++qs) {
        const size_t qo = (size_t)(b * SEQ + qrow0[qs] + l) * DMODEL + h * 64 + 8 * g;
        qf[qs][0] = *reinterpret_cast<const bf16x8*>(&Q[qo]);
        qf[qs][1] = *reinterpret_cast<const bf16x8*>(&Q[qo + 32]);
    }

    f32x4 accO[2][4];
    #pragma unroll
    for (int qs = 0; qs < 2; ++qs)
        #pragma unroll
        for (int dt = 0; dt < 4; ++dt) accO[qs][dt] = (f32x4){0.f, 0.f, 0.f, 0.f};
    float m_i[2] = {-INFINITY, -INFINITY}, l_i[2] = {0.f, 0.f};

    bf16x8 kf0[4][2], vf0[4][2], kf1[4][2], vf1[4][2];

    auto LOADK = [&](bf16x8 (&kf)[4][2], int kc) {
        const int k0 = kc * 64;
        #pragma unroll
        for (int nt = 0; nt < 4; ++nt) {
            const size_t ko = kbase + (size_t)(k0 + nt * 16 + l) * DMODEL + 8 * g;
            kf[nt][0] = *reinterpret_cast<const bf16x8*>(&K[ko]);
            kf[nt][1] = *reinterpret_cast<const bf16x8*>(&K[ko + 32]);
        }
    };
    auto LOADV = [&](bf16x8 (&vf)[4][2], int kc) {
        const int k0 = kc * 64;
        #pragma unroll
        for (int dt = 0; dt < 4; ++dt) {
            const size_t vo = vbase + (size_t)(dt * 16 + l) * SEQ + k0 + 8 * g;
            vf[dt][0] = *reinterpret_cast<const bf16x8*>(&Vt[vo]);
            vf[dt][1] = *reinterpret_cast<const bf16x8*>(&Vt[vo + 32]);
        }
    };

    auto COMPUTE = [&](int kc, bf16x8 (&kf)[4][2], bf16x8 (&vf)[4][2]) {
        const int k0 = kc * 64;
        const bool doA = (kc < nchA);

        // swapped QK^T: sc[qs][nt][r] = score[key=k0+16nt+4g+r][q=qrow0+l]
        f32x4 sc[2][4];
        #pragma unroll
        for (int nt = 0; nt < 4; ++nt) {
            f32x4 z = (f32x4){0.f, 0.f, 0.f, 0.f};
            z = __builtin_amdgcn_mfma_f32_16x16x32_bf16(kf[nt][0], qf[1][0], z, 0, 0, 0);
            z = __builtin_amdgcn_mfma_f32_16x16x32_bf16(kf[nt][1], qf[1][1], z, 0, 0, 0);
            sc[1][nt] = z;
        }
        if (doA) {
            #pragma unroll
            for (int nt = 0; nt < 4; ++nt) {
                f32x4 z = (f32x4){0.f, 0.f, 0.f, 0.f};
                z = __builtin_amdgcn_mfma_f32_16x16x32_bf16(kf[nt][0], qf[0][0], z, 0, 0, 0);
                z = __builtin_amdgcn_mfma_f32_16x16x32_bf16(kf[nt][1], qf[0][1], z, 0, 0, 0);
                sc[0][nt] = z;
            }
        }

        // causal mask on each set's diagonal chunk
        #pragma unroll
        for (int qs = 0; qs < 2; ++qs) {
            if (kc == ((qs == 0) ? nchA : nchB) - 1) {
                const int qg = qrow0[qs] + l;
                #pragma unroll
                for (int nt = 0; nt < 4; ++nt)
                    #pragma unroll
                    for (int r = 0; r < 4; ++r)
                        if (k0 + nt * 16 + g * 4 + r > qg) sc[qs][nt][r] = -INFINITY;
            }
        }

        // online softmax (exp2 domain), tree reductions
        #pragma unroll
        for (int qs = 0; qs < 2; ++qs) {
            if (qs == 0 && !doA) continue;
            float mc = fmaxf(fmaxf(vmax4(sc[qs][0]), vmax4(sc[qs][1])),
                             fmaxf(vmax4(sc[qs][2]), vmax4(sc[qs][3])));
            mc = fmaxf(mc, __shfl_xor(mc, 16, 64));
            mc = fmaxf(mc, __shfl_xor(mc, 32, 64));

            if (__any(mc > m_i[qs] + 8.f)) {          // defer-max rescale
                const float mn = fmaxf(m_i[qs], mc);
                const float al = exp2f(m_i[qs] - mn);
                m_i[qs] = mn;
                l_i[qs] *= al;
                #pragma unroll
                for (int r = 0; r < 4; ++r) {
                    const float ar = __shfl(al, 4 * g + r, 64);
                    #pragma unroll
                    for (int dt = 0; dt < 4; ++dt) accO[qs][dt][r] *= ar;
                }
            }

            float psum[4];
            #pragma unroll
            for (int nt = 0; nt < 4; ++nt) {
                #pragma unroll
                for (int r = 0; r < 4; ++r)
                    sc[qs][nt][r] = exp2f(sc[qs][nt][r] - m_i[qs]);
                psum[nt] = (sc[qs][nt][0] + sc[qs][nt][1]) + (sc[qs][nt][2] + sc[qs][nt][3]);
            }
            float rs = (psum[0] + psum[1]) + (psum[2] + psum[3]);
            rs += __shfl_xor(rs, 16, 64);
            rs += __shfl_xor(rs, 32, 64);
            l_i[qs] += rs;

            const int prow = w * 32 + qs * 16 + l;
            #pragma unroll
            for (int nt = 0; nt < 4; ++nt)
                *reinterpret_cast<ushort4*>(&Pl[prow * LDP + nt * 16 + 4 * g]) =
                    pack4bf(sc[qs][nt][0], sc[qs][nt][1], sc[qs][nt][2], sc[qs][nt][3]);
        }

        // PV
        #pragma unroll
        for (int qs = 0; qs < 2; ++qs) {
            if (qs == 0 && !doA) continue;
            bf16x8 pf[2];
            const int prow = w * 32 + qs * 16 + l;
            pf[0] = *reinterpret_cast<const bf16x8*>(&Pl[prow * LDP + 8 * g]);
            pf[1] = *reinterpret_cast<const bf16x8*>(&Pl[prow * LDP + 32 + 8 * g]);
            #pragma unroll
            for (int dt = 0; dt < 4; ++dt) {
                accO[qs][dt] = __builtin_amdgcn_mfma_f32_16x16x32_bf16(pf[0], vf[dt][0], accO[qs][dt], 0, 0, 0);
                accO[qs][dt] = __builtin_amdgcn_mfma_f32_16x16x32_bf16(pf[1], vf[dt][1], accO[qs][dt], 0, 0, 0);
            }
        }
    };

    // prologue: chunk 0 into buffer 0
    LOADK(kf0, 0); LOADV(vf0, 0);

    for (int kc = 0; kc < nchB; kc += 2) {
        const int n1 = (kc + 1 < nchB) ? kc + 1 : kc;     // clamped (redundant ok)
        LOADK(kf1, n1); LOADV(vf1, n1);
        COMPUTE(kc, kf0, vf0);

        const int n2 = (kc + 2 < nchB) ? kc + 2 : n1;
        LOADK(kf0, n2); LOADV(vf0, n2);
        if (kc + 1 < nchB) COMPUTE(kc + 1, kf1, vf1);
    }

    // epilogue: normalize, emit attended hi/lo bf16
    #pragma unroll
    for (int qs = 0; qs < 2; ++qs) {
        #pragma unroll
        for (int r = 0; r < 4; ++r) {
            const float lr = __shfl(l_i[qs], 4 * g + r, 64);
            const float inv = 1.f / lr;
            const size_t row = (size_t)(b * SEQ + qrow0[qs] + g * 4 + r) * DMODEL + h * 64;
            #pragma unroll
            for (int dt = 0; dt < 4; ++dt) {
                const float val = accO[qs][dt][r] * inv;
                const ushort hh = f2bf(val);
                ATh[row + dt * 16 + l] = hh;
                ATl[row + dt * 16 + l] = f2bf(val - bf2f(hh));
            }
        }
    }
}

// ---------------- out GEMM: 3-pass hi/lo, 128x64 tile, BK=64, fp32 out ----------------
__global__ __launch_bounds__(512) void gemm_o(const ushort* __restrict__ Ahg,
                                              const ushort* __restrict__ Alg,
                                              const ushort* __restrict__ Bhg,
                                              const ushort* __restrict__ Blg,
                                              float* __restrict__ C) {
    __shared__ ushort SH[24576];
    ushort* const Ah = SH;
    ushort* const Al = SH + 8192;
    ushort* const Bh = SH + 16384;
    ushort* const Bl = SH + 20480;

    const int t = threadIdx.x, lane = t & 63, w = t >> 6;
    const int l = lane & 15, g = lane >> 4;
    const int wm = w >> 1, wn = w & 1;
    const int bm = blockIdx.y * 128, bn = blockIdx.x * 64;

    f32x4 acc[2][2];
    #pragma unroll
    for (int mt = 0; mt < 2; ++mt)
        #pragma unroll
        for (int nt = 0; nt < 2; ++nt) acc[mt][nt] = (f32x4){0.f, 0.f, 0.f, 0.f};

    for (int kt = 0; kt < DMODEL; kt += 64) {
        __syncthreads();
        #pragma unroll
        for (int i = 0; i < 6; ++i) {
            const int sid = w * 6 + i;
            const ushort* src; ushort* dst; int rb, c;
            if (sid < 16)      { src = Ahg; dst = Ah; rb = bm; c = sid; }
            else if (sid < 32) { src = Alg; dst = Al; rb = bm; c = sid - 16; }
            else if (sid < 40) { src = Bhg; dst = Bh; rb = bn; c = sid - 32; }
            else               { src = Blg; dst = Bl; rb = bn; c = sid - 40; }
            const int row = c * 8 + (lane >> 3);
            const int sw = ((lane & 7) ^ (row & 7)) << 3;
            GLD16(src + (size_t)(rb + row) * DMODEL + kt + sw, dst + c * 512);
        }
        __syncthreads();

        bf16x8 ah[2][2], al[2][2], bhf[2][2], blf[2][2];
        #pragma unroll
        for (int mt = 0; mt < 2; ++mt)
            #pragma unroll
            for (int s = 0; s < 2; ++s) {
                const int m = wm * 32 + mt * 16 + l;
                const int off = m * 64 + (((g + 4 * s) ^ (m & 7)) << 3);
                ah[mt][s] = *reinterpret_cast<const bf16x8*>(&Ah[off]);
                al[mt][s] = *reinterpret_cast<const bf16x8*>(&Al[off]);
            }
        #pragma unroll
        for (int nt = 0; nt < 2; ++nt)
            #pragma unroll
            for (int s = 0; s < 2; ++s) {
                const int n = wn * 32 + nt * 16 + l;
                const int off = n * 64 + (((g + 4 * s) ^ (n & 7)) << 3);
                bhf[nt][s] = *reinterpret_cast<const bf16x8*>(&Bh[off]);
                blf[nt][s] = *reinterpret_cast<const bf16x8*>(&Bl[off]);
            }
        #pragma unroll
        for (int mt = 0; mt < 2; ++mt)
            #pragma unroll
            for (int nt = 0; nt < 2; ++nt)
                #pragma unroll
                for (int s = 0; s < 2; ++s) {
                    acc[mt][nt] = __builtin_amdgcn_mfma_f32_16x16x32_bf16(ah[mt][s], bhf[nt][s], acc[mt][nt], 0, 0, 0);
                    acc[mt][nt] = __builtin_amdgcn_mfma_f32_16x16x32_bf16(ah[mt][s], blf[nt][s], acc[mt][nt], 0, 0, 0);
                    acc[mt][nt] = __builtin_amdgcn_mfma_f32_16x16x32_bf16(al[mt][s], bhf[nt][s], acc[mt][nt], 0, 0, 0);
                }
    }

    #pragma unroll
    for (int mt = 0; mt < 2; ++mt)
        #pragma unroll
        for (int nt = 0; nt < 2; ++nt)
            #pragma unroll
            for (int r = 0; r < 4; ++r) {
                const int row = bm + wm * 32 + mt * 16 + g * 4 + r;
                const int col = bn + wn * 32 + nt * 16 + l;
                C[(size_t)row * DMODEL + col] = acc[mt][nt][r];
            }
}

// ---------------- launch ----------------
extern "C" void kernel_launch(void* const* d_in, const int* in_sizes, int n_in,
                              void* d_out, int out_size, void* d_ws, size_t ws_size,
                              hipStream_t stream) {
    const float* x  = (const float*)d_in[0];
    const float* Wq = (const float*)d_in[1];
    const float* Wk = (const float*)d_in[2];
    const float* Wv = (const float*)d_in[3];
    const float* Wo = (const float*)d_in[4];
    float* out = (float*)d_out;

    char* ws = (char*)d_ws;
    const size_t MB = 1024 * 1024;
    ushort* xh  = (ushort*)(ws);              // 8 MB  (aliased as ATh after QKV gemm)
    ushort* ath = xh;
    ushort* atl = (ushort*)(ws + 8 * MB);     // 8 MB
    ushort* wtc = (ushort*)(ws + 16 * MB);    // 6 MB  [3072][1024]
    ushort* woh = (ushort*)(ws + 22 * MB);    // 2 MB
    ushort* wol = (ushort*)(ws + 24 * MB);    // 2 MB
    ushort* Qb  = (ushort*)(ws + 26 * MB);    // 8 MB
    ushort* Kb  = (ushort*)(ws + 34 * MB);    // 8 MB
    ushort* Vtb = (ushort*)(ws + 42 * MB);    // 8 MB

    split_x<<<1024, 256, 0, stream>>>(x, xh, MROWS * DMODEL / 4);
    tsplit_w<<<dim3(16, 16, 4), 256, 0, stream>>>(Wq, Wk, Wv, Wo, wtc, woh, wol);

    gemm_qkv<<<dim3(24, 32), 512, 0, stream>>>(xh, wtc, Qb, Kb, Vtb);

    attn<<<dim3(32, 16), 256, 0, stream>>>(Qb, Kb, Vtb, ath, atl);

    gemm_o<<<dim3(16, 32), 512, 0, stream>>>(ath, atl, woh, wol, out);
}

// Round 10
// 136.091 us; speedup vs baseline: 1.4009x; 1.4009x over previous
//
#include <hip/hip_runtime.h>
#include <math.h>

#define BATCH 2
#define SEQ   2048
#define DMODEL 1024
#define NHEAD 16
#define HEADD 64
#define MROWS 4096

typedef __attribute__((ext_vector_type(8))) __bf16 bf16x8;
typedef __attribute__((ext_vector_type(4))) float f32x4;

__device__ __forceinline__ ushort f2bf(float f) {
    uint u = __float_as_uint(f);
    u += 0x7fffu + ((u >> 16) & 1u);
    return (ushort)(u >> 16);
}
__device__ __forceinline__ float bf2f(ushort h) {
    return __uint_as_float(((uint)h) << 16);
}
__device__ __forceinline__ ushort4 pack4bf(float a, float b, float c, float d) {
    union { __bf16 h[4]; ushort4 u; } p;
    p.h[0] = (__bf16)a; p.h[1] = (__bf16)b; p.h[2] = (__bf16)c; p.h[3] = (__bf16)d;
    return p.u;
}
__device__ __forceinline__ float vmax4(const f32x4 v) {
    return fmaxf(fmaxf(v[0], v[1]), fmaxf(v[2], v[3]));
}

#define GLD16(gsrc, ldst)                                                         \
    __builtin_amdgcn_global_load_lds(                                             \
        (const __attribute__((address_space(1))) unsigned int*)(gsrc),            \
        (__attribute__((address_space(3))) unsigned int*)(ldst), 16, 0, 0)

// Q pre-scale: (1/sqrt(64)) * log2(e)  -> softmax in exp2 domain
#define QSCALE 0.1803368801111204f

// ---------------- prep: x fp32 -> bf16 (hi only) ----------------
__global__ __launch_bounds__(256) void split_x(const float* __restrict__ in,
                                               ushort* __restrict__ oh, int n4) {
    int i = blockIdx.x * 256 + threadIdx.x;
    const int stride = gridDim.x * 256;
    for (; i < n4; i += stride) {
        const float4 v = reinterpret_cast<const float4*>(in)[i];
        ushort4 h;
        h.x = f2bf(v.x); h.y = f2bf(v.y); h.z = f2bf(v.z); h.w = f2bf(v.w);
        reinterpret_cast<ushort4*>(oh)[i] = h;
    }
}

// ---------------- prep: W^T; z<3 -> combined QKV hi; z==3 -> Wo hi/lo ----------------
__global__ __launch_bounds__(256) void tsplit_w(const float* __restrict__ Wq,
                                                const float* __restrict__ Wk,
                                                const float* __restrict__ Wv,
                                                const float* __restrict__ Wo,
                                                ushort* __restrict__ wtc,
                                                ushort* __restrict__ woh,
                                                ushort* __restrict__ wol) {
    const int z = blockIdx.z;
    const float* W = (z == 0) ? Wq : (z == 1) ? Wk : (z == 2) ? Wv : Wo;
    __shared__ float T[64][68];
    const int t = threadIdx.x;
    const int k0 = blockIdx.y * 64, n0 = blockIdx.x * 64;
    {
        const int r = t >> 2, c0 = (t & 3) * 16;
        #pragma unroll
        for (int j = 0; j < 4; ++j)
            *reinterpret_cast<float4*>(&T[r][c0 + j * 4]) =
                *reinterpret_cast<const float4*>(&W[(size_t)(k0 + r) * DMODEL + n0 + c0 + j * 4]);
    }
    __syncthreads();
    const int nl = t >> 2, kq = t & 3;
    if (z < 3) {
        ushort hb[16];
        #pragma unroll
        for (int e = 0; e < 16; ++e) hb[e] = f2bf(T[kq * 16 + e][nl]);
        const size_t o = (size_t)(z * 1024 + n0 + nl) * DMODEL + k0 + kq * 16;
        *reinterpret_cast<uint4*>(&wtc[o]) = *reinterpret_cast<uint4*>(&hb[0]);
        *reinterpret_cast<uint4*>(&wtc[o + 8]) = *reinterpret_cast<uint4*>(&hb[8]);
    } else {
        ushort hb[16], lb[16];
        #pragma unroll
        for (int e = 0; e < 16; ++e) {
            const float v = T[kq * 16 + e][nl];
            const ushort h = f2bf(v);
            hb[e] = h; lb[e] = f2bf(v - bf2f(h));
        }
        const size_t o = (size_t)(n0 + nl) * DMODEL + k0 + kq * 16;
        *reinterpret_cast<uint4*>(&woh[o]) = *reinterpret_cast<uint4*>(&hb[0]);
        *reinterpret_cast<uint4*>(&woh[o + 8]) = *reinterpret_cast<uint4*>(&hb[8]);
        *reinterpret_cast<uint4*>(&wol[o]) = *reinterpret_cast<uint4*>(&lb[0]);
        *reinterpret_cast<uint4*>(&wol[o + 8]) = *reinterpret_cast<uint4*>(&lb[8]);
    }
}

// ---------------- fused QKV GEMM: single-pass bf16, 128x128 tile, BK=64 ----------------
__global__ __launch_bounds__(512) void gemm_qkv(const ushort* __restrict__ xh,
                                                const ushort* __restrict__ wtc,
                                                ushort* __restrict__ Qb,
                                                ushort* __restrict__ Kb,
                                                ushort* __restrict__ Vtb) {
    __shared__ ushort SH[17408];
    ushort* const Ah = SH;
    ushort* const Bh = SH + 8192;

    const int t = threadIdx.x, lane = t & 63, w = t >> 6;
    const int l = lane & 15, g = lane >> 4;
    const int wm = w >> 2, wn = w & 3;
    const int bm = blockIdx.y * 128, bn = blockIdx.x * 128;

    f32x4 acc[4][2];
    #pragma unroll
    for (int mt = 0; mt < 4; ++mt)
        #pragma unroll
        for (int nt = 0; nt < 2; ++nt) acc[mt][nt] = (f32x4){0.f, 0.f, 0.f, 0.f};

    for (int kt = 0; kt < DMODEL; kt += 64) {
        __syncthreads();
        #pragma unroll
        for (int i = 0; i < 4; ++i) {
            const int sid = w * 4 + i;
            const int c = sid & 15;
            const ushort* src = (sid < 16) ? xh : wtc;
            const int rb = (sid < 16) ? bm : bn;
            ushort* dst = ((sid < 16) ? Ah : Bh) + c * 512;
            const int row = c * 8 + (lane >> 3);
            const int sw = ((lane & 7) ^ (row & 7)) << 3;
            GLD16(src + (size_t)(rb + row) * DMODEL + kt + sw, dst);
        }
        __syncthreads();

        bf16x8 af[4][2], bf[2][2];
        #pragma unroll
        for (int mt = 0; mt < 4; ++mt)
            #pragma unroll
            for (int s = 0; s < 2; ++s) {
                const int m = wm * 64 + mt * 16 + l;
                af[mt][s] = *reinterpret_cast<const bf16x8*>(&Ah[m * 64 + (((g + 4 * s) ^ (m & 7)) << 3)]);
            }
        #pragma unroll
        for (int nt = 0; nt < 2; ++nt)
            #pragma unroll
            for (int s = 0; s < 2; ++s) {
                const int n = wn * 32 + nt * 16 + l;
                bf[nt][s] = *reinterpret_cast<const bf16x8*>(&Bh[n * 64 + (((g + 4 * s) ^ (n & 7)) << 3)]);
            }
        #pragma unroll
        for (int mt = 0; mt < 4; ++mt)
            #pragma unroll
            for (int nt = 0; nt < 2; ++nt)
                #pragma unroll
                for (int s = 0; s < 2; ++s)
                    acc[mt][nt] = __builtin_amdgcn_mfma_f32_16x16x32_bf16(af[mt][s], bf[nt][s], acc[mt][nt], 0, 0, 0);
    }

    const int mode = bn >> 10;
    if (mode == 0) {
        #pragma unroll
        for (int mt = 0; mt < 4; ++mt)
            #pragma unroll
            for (int nt = 0; nt < 2; ++nt)
                #pragma unroll
                for (int r = 0; r < 4; ++r) {
                    const int row = bm + wm * 64 + mt * 16 + g * 4 + r;
                    const int col = bn + wn * 32 + nt * 16 + l;
                    Qb[(size_t)row * DMODEL + col] = f2bf(acc[mt][nt][r] * QSCALE);
                }
    } else if (mode == 1) {
        #pragma unroll
        for (int mt = 0; mt < 4; ++mt)
            #pragma unroll
            for (int nt = 0; nt < 2; ++nt)
                #pragma unroll
                for (int r = 0; r < 4; ++r) {
                    const int row = bm + wm * 64 + mt * 16 + g * 4 + r;
                    const int col = (bn - 1024) + wn * 32 + nt * 16 + l;
                    Kb[(size_t)row * DMODEL + col] = f2bf(acc[mt][nt][r]);
                }
    } else {
        __syncthreads();
        ushort* VtL = SH;   // [128 d][136 key]
        #pragma unroll
        for (int mt = 0; mt < 4; ++mt)
            #pragma unroll
            for (int nt = 0; nt < 2; ++nt)
                #pragma unroll
                for (int r = 0; r < 4; ++r) {
                    const int dl = wn * 32 + nt * 16 + l;
                    const int kl = wm * 64 + mt * 16 + g * 4 + r;
                    VtL[dl * 136 + kl] = f2bf(acc[mt][nt][r]);
                }
        __syncthreads();
        const int dl = t >> 2, kq = t & 3;
        const int b = bm >> 11;
        const int row = b * 1024 + (bn - 2048) + dl;
        const int key0 = bm & 2047;
        const size_t o = (size_t)row * SEQ + key0 + kq * 32;
        #pragma unroll
        for (int j = 0; j < 4; ++j)
            *reinterpret_cast<uint4*>(&Vtb[o + j * 8]) =
                *reinterpret_cast<uint4*>(&VtL[dl * 136 + kq * 32 + j * 8]);
    }
}

// ---------------- attention: LDS-staged K/V (double-buffered), paired tiles ----------------
// Grid (x=bh 32, y=pair 16): XCD-local bh. Block = 256 thr (4 waves).
// Per chunk: waves 0-1 stage the 8KB K chunk, waves 2-3 stage the 8KB V^T chunk
// via global_load_lds (coalesced, XOR-swizzled source). Double buffer; one
// barrier per chunk. Fragments read as swizzled ds_read_b128.
#define LDP 72

__global__ __launch_bounds__(256, 2) void attn(const ushort* __restrict__ Q,
                                               const ushort* __restrict__ K,
                                               const ushort* __restrict__ Vt,
                                               ushort* __restrict__ ATh,
                                               ushort* __restrict__ ATl) {
    __shared__ ushort Kl[2 * 4096];    // [buf][key 64][d 64] swizzled
    __shared__ ushort Vl[2 * 4096];    // [buf][d 64][key 64] swizzled
    __shared__ ushort Pl[128 * LDP];   // wave-private P rows

    const int t = threadIdx.x, lane = t & 63, w = t >> 6;
    const int l = lane & 15, g = lane >> 4;
    const int pair = blockIdx.y;                  // 0..15
    const int tA = pair, tB = 31 - pair;
    const int bh = blockIdx.x, b = bh >> 4, h = bh & 15;
    const size_t kbase = (size_t)b * SEQ * DMODEL + h * 64;
    const size_t vbase = (size_t)bh * 64 * SEQ;
    const int qrow0[2] = {tA * 64 + w * 16, tB * 64 + w * 16};
    const int nchA = tA + 1, nchB = tB + 1;       // nchA <= 16 < nchB

    // Q B-operand frags (col=q=lane&15, k=d=32s+8g+e)
    bf16x8 qf[2][2];
    #pragma unroll
    for (int qs = 0; qs < 2; ++qs) {
        const size_t qo = (size_t)(b * SEQ + qrow0[qs] + l) * DMODEL + h * 64 + 8 * g;
        qf[qs][0] = *reinterpret_cast<const bf16x8*>(&Q[qo]);
        qf[qs][1] = *reinterpret_cast<const bf16x8*>(&Q[qo + 32]);
    }

    f32x4 accO[2][4];
    #pragma unroll
    for (int qs = 0; qs < 2; ++qs)
        #pragma unroll
        for (int dt = 0; dt < 4; ++dt) accO[qs][dt] = (f32x4){0.f, 0.f, 0.f, 0.f};
    float m_i[2] = {-INFINITY, -INFINITY}, l_i[2] = {0.f, 0.f};

    // stage one 64-key chunk into LDS buffer `buf` (async, 4 GLD16 per wave)
    auto STAGE = [&](int buf, int kc) {
        const int k0 = kc * 64;
        if (w < 2) {
            #pragma unroll
            for (int i = 0; i < 4; ++i) {
                const int c = w * 4 + i;              // 0..7 (8 rows each)
                const int row = c * 8 + (lane >> 3);  // key 0..63
                const int sw = ((lane & 7) ^ (row & 7)) << 3;
                GLD16(K + kbase + (size_t)(k0 + row) * DMODEL + sw,
                      Kl + buf * 4096 + c * 512);
            }
        } else {
            #pragma unroll
            for (int i = 0; i < 4; ++i) {
                const int c = (w - 2) * 4 + i;
                const int row = c * 8 + (lane >> 3);  // d 0..63
                const int sw = ((lane & 7) ^ (row & 7)) << 3;
                GLD16(Vt + vbase + (size_t)row * SEQ + k0 + sw,
                      Vl + buf * 4096 + c * 512);
            }
        }
    };

    auto COMPUTE = [&](int buf, int kc) {
        const int k0 = kc * 64;
        const bool doA = (kc < nchA);
        const ushort* Kb_ = Kl + buf * 4096;
        const ushort* Vb_ = Vl + buf * 4096;
        const int xorsw0 = ((g + 0) ^ (l & 7)) << 3;
        const int xorsw1 = ((g + 4) ^ (l & 7)) << 3;

        // K frags from LDS (row=key=16nt+l)
        bf16x8 kf[4][2];
        #pragma unroll
        for (int nt = 0; nt < 4; ++nt) {
            const int ro = (nt * 16 + l) * 64;
            kf[nt][0] = *reinterpret_cast<const bf16x8*>(&Kb_[ro + xorsw0]);
            kf[nt][1] = *reinterpret_cast<const bf16x8*>(&Kb_[ro + xorsw1]);
        }

        // swapped QK^T: sc[qs][nt][r] = score[key=k0+16nt+4g+r][q=qrow0+l]
        f32x4 sc[2][4];
        #pragma unroll
        for (int nt = 0; nt < 4; ++nt) {
            f32x4 z = (f32x4){0.f, 0.f, 0.f, 0.f};
            z = __builtin_amdgcn_mfma_f32_16x16x32_bf16(kf[nt][0], qf[1][0], z, 0, 0, 0);
            z = __builtin_amdgcn_mfma_f32_16x16x32_bf16(kf[nt][1], qf[1][1], z, 0, 0, 0);
            sc[1][nt] = z;
        }
        if (doA) {
            #pragma unroll
            for (int nt = 0; nt < 4; ++nt) {
                f32x4 z = (f32x4){0.f, 0.f, 0.f, 0.f};
                z = __builtin_amdgcn_mfma_f32_16x16x32_bf16(kf[nt][0], qf[0][0], z, 0, 0, 0);
                z = __builtin_amdgcn_mfma_f32_16x16x32_bf16(kf[nt][1], qf[0][1], z, 0, 0, 0);
                sc[0][nt] = z;
            }
        }

        // causal mask on each set's diagonal chunk
        #pragma unroll
        for (int qs = 0; qs < 2; ++qs) {
            if (kc == ((qs == 0) ? nchA : nchB) - 1) {
                const int qg = qrow0[qs] + l;
                #pragma unroll
                for (int nt = 0; nt < 4; ++nt)
                    #pragma unroll
                    for (int r = 0; r < 4; ++r)
                        if (k0 + nt * 16 + g * 4 + r > qg) sc[qs][nt][r] = -INFINITY;
            }
        }

        // online softmax (exp2 domain), tree reductions
        #pragma unroll
        for (int qs = 0; qs < 2; ++qs) {
            if (qs == 0 && !doA) continue;
            float mc = fmaxf(fmaxf(vmax4(sc[qs][0]), vmax4(sc[qs][1])),
                             fmaxf(vmax4(sc[qs][2]), vmax4(sc[qs][3])));
            mc = fmaxf(mc, __shfl_xor(mc, 16, 64));
            mc = fmaxf(mc, __shfl_xor(mc, 32, 64));

            if (__any(mc > m_i[qs] + 8.f)) {          // defer-max rescale
                const float mn = fmaxf(m_i[qs], mc);
                const float al = exp2f(m_i[qs] - mn);
                m_i[qs] = mn;
                l_i[qs] *= al;
                #pragma unroll
                for (int r = 0; r < 4; ++r) {
                    const float ar = __shfl(al, 4 * g + r, 64);
                    #pragma unroll
                    for (int dt = 0; dt < 4; ++dt) accO[qs][dt][r] *= ar;
                }
            }

            float psum[4];
            #pragma unroll
            for (int nt = 0; nt < 4; ++nt) {
                #pragma unroll
                for (int r = 0; r < 4; ++r)
                    sc[qs][nt][r] = exp2f(sc[qs][nt][r] - m_i[qs]);
                psum[nt] = (sc[qs][nt][0] + sc[qs][nt][1]) + (sc[qs][nt][2] + sc[qs][nt][3]);
            }
            float rs = (psum[0] + psum[1]) + (psum[2] + psum[3]);
            rs += __shfl_xor(rs, 16, 64);
            rs += __shfl_xor(rs, 32, 64);
            l_i[qs] += rs;

            const int prow = w * 32 + qs * 16 + l;
            #pragma unroll
            for (int nt = 0; nt < 4; ++nt)
                *reinterpret_cast<ushort4*>(&Pl[prow * LDP + nt * 16 + 4 * g]) =
                    pack4bf(sc[qs][nt][0], sc[qs][nt][1], sc[qs][nt][2], sc[qs][nt][3]);
        }

        // V frags from LDS (row=d=16dt+l) + PV
        bf16x8 vf[4][2];
        #pragma unroll
        for (int dt = 0; dt < 4; ++dt) {
            const int ro = (dt * 16 + l) * 64;
            vf[dt][0] = *reinterpret_cast<const bf16x8*>(&Vb_[ro + xorsw0]);
            vf[dt][1] = *reinterpret_cast<const bf16x8*>(&Vb_[ro + xorsw1]);
        }
        #pragma unroll
        for (int qs = 0; qs < 2; ++qs) {
            if (qs == 0 && !doA) continue;
            bf16x8 pf[2];
            const int prow = w * 32 + qs * 16 + l;
            pf[0] = *reinterpret_cast<const bf16x8*>(&Pl[prow * LDP + 8 * g]);
            pf[1] = *reinterpret_cast<const bf16x8*>(&Pl[prow * LDP + 32 + 8 * g]);
            #pragma unroll
            for (int dt = 0; dt < 4; ++dt) {
                accO[qs][dt] = __builtin_amdgcn_mfma_f32_16x16x32_bf16(pf[0], vf[dt][0], accO[qs][dt], 0, 0, 0);
                accO[qs][dt] = __builtin_amdgcn_mfma_f32_16x16x32_bf16(pf[1], vf[dt][1], accO[qs][dt], 0, 0, 0);
            }
        }
    };

    // prologue: stage chunk 0 into buffer 0
    STAGE(0, 0);
    __syncthreads();

    int cur = 0;
    for (int kc = 0; kc < nchB; ++kc) {
        if (kc + 1 < nchB) STAGE(cur ^ 1, kc + 1);   // async prefetch into other buffer
        COMPUTE(cur, kc);
        __syncthreads();   // drains vmcnt (prefetch landed) + all reads of cur done
        cur ^= 1;
    }

    // epilogue: normalize, emit attended hi/lo bf16
    #pragma unroll
    for (int qs = 0; qs < 2; ++qs) {
        #pragma unroll
        for (int r = 0; r < 4; ++r) {
            const float lr = __shfl(l_i[qs], 4 * g + r, 64);
            const float inv = 1.f / lr;
            const size_t row = (size_t)(b * SEQ + qrow0[qs] + g * 4 + r) * DMODEL + h * 64;
            #pragma unroll
            for (int dt = 0; dt < 4; ++dt) {
                const float val = accO[qs][dt][r] * inv;
                const ushort hh = f2bf(val);
                ATh[row + dt * 16 + l] = hh;
                ATl[row + dt * 16 + l] = f2bf(val - bf2f(hh));
            }
        }
    }
}

// ---------------- out GEMM: 3-pass hi/lo, 128x64 tile, BK=64, fp32 out ----------------
__global__ __launch_bounds__(512) void gemm_o(const ushort* __restrict__ Ahg,
                                              const ushort* __restrict__ Alg,
                                              const ushort* __restrict__ Bhg,
                                              const ushort* __restrict__ Blg,
                                              float* __restrict__ C) {
    __shared__ ushort SH[24576];
    ushort* const Ah = SH;
    ushort* const Al = SH + 8192;
    ushort* const Bh = SH + 16384;
    ushort* const Bl = SH + 20480;

    const int t = threadIdx.x, lane = t & 63, w = t >> 6;
    const int l = lane & 15, g = lane >> 4;
    const int wm = w >> 1, wn = w & 1;
    const int bm = blockIdx.y * 128, bn = blockIdx.x * 64;

    f32x4 acc[2][2];
    #pragma unroll
    for (int mt = 0; mt < 2; ++mt)
        #pragma unroll
        for (int nt = 0; nt < 2; ++nt) acc[mt][nt] = (f32x4){0.f, 0.f, 0.f, 0.f};

    for (int kt = 0; kt < DMODEL; kt += 64) {
        __syncthreads();
        #pragma unroll
        for (int i = 0; i < 6; ++i) {
            const int sid = w * 6 + i;
            const ushort* src; ushort* dst; int rb, c;
            if (sid < 16)      { src = Ahg; dst = Ah; rb = bm; c = sid; }
            else if (sid < 32) { src = Alg; dst = Al; rb = bm; c = sid - 16; }
            else if (sid < 40) { src = Bhg; dst = Bh; rb = bn; c = sid - 32; }
            else               { src = Blg; dst = Bl; rb = bn; c = sid - 40; }
            const int row = c * 8 + (lane >> 3);
            const int sw = ((lane & 7) ^ (row & 7)) << 3;
            GLD16(src + (size_t)(rb + row) * DMODEL + kt + sw, dst + c * 512);
        }
        __syncthreads();

        bf16x8 ah[2][2], al[2][2], bhf[2][2], blf[2][2];
        #pragma unroll
        for (int mt = 0; mt < 2; ++mt)
            #pragma unroll
            for (int s = 0; s < 2; ++s) {
                const int m = wm * 32 + mt * 16 + l;
                const int off = m * 64 + (((g + 4 * s) ^ (m & 7)) << 3);
                ah[mt][s] = *reinterpret_cast<const bf16x8*>(&Ah[off]);
                al[mt][s] = *reinterpret_cast<const bf16x8*>(&Al[off]);
            }
        #pragma unroll
        for (int nt = 0; nt < 2; ++nt)
            #pragma unroll
            for (int s = 0; s < 2; ++s) {
                const int n = wn * 32 + nt * 16 + l;
                const int off = n * 64 + (((g + 4 * s) ^ (n & 7)) << 3);
                bhf[nt][s] = *reinterpret_cast<const bf16x8*>(&Bh[off]);
                blf[nt][s] = *reinterpret_cast<const bf16x8*>(&Bl[off]);
            }
        #pragma unroll
        for (int mt = 0; mt < 2; ++mt)
            #pragma unroll
            for (int nt = 0; nt < 2; ++nt)
                #pragma unroll
                for (int s = 0; s < 2; ++s) {
                    acc[mt][nt] = __builtin_amdgcn_mfma_f32_16x16x32_bf16(ah[mt][s], bhf[nt][s], acc[mt][nt], 0, 0, 0);
                    acc[mt][nt] = __builtin_amdgcn_mfma_f32_16x16x32_bf16(ah[mt][s], blf[nt][s], acc[mt][nt], 0, 0, 0);
                    acc[mt][nt] = __builtin_amdgcn_mfma_f32_16x16x32_bf16(al[mt][s], bhf[nt][s], acc[mt][nt], 0, 0, 0);
                }
    }

    #pragma unroll
    for (int mt = 0; mt < 2; ++mt)
        #pragma unroll
        for (int nt = 0; nt < 2; ++nt)
            #pragma unroll
            for (int r = 0; r < 4; ++r) {
                const int row = bm + wm * 32 + mt * 16 + g * 4 + r;
                const int col = bn + wn * 32 + nt * 16 + l;
                C[(size_t)row * DMODEL + col] = acc[mt][nt][r];
            }
}

// ---------------- launch ----------------
extern "C" void kernel_launch(void* const* d_in, const int* in_sizes, int n_in,
                              void* d_out, int out_size, void* d_ws, size_t ws_size,
                              hipStream_t stream) {
    const float* x  = (const float*)d_in[0];
    const float* Wq = (const float*)d_in[1];
    const float* Wk = (const float*)d_in[2];
    const float* Wv = (const float*)d_in[3];
    const float* Wo = (const float*)d_in[4];
    float* out = (float*)d_out;

    char* ws = (char*)d_ws;
    const size_t MB = 1024 * 1024;
    ushort* xh  = (ushort*)(ws);              // 8 MB  (aliased as ATh after QKV gemm)
    ushort* ath = xh;
    ushort* atl = (ushort*)(ws + 8 * MB);     // 8 MB
    ushort* wtc = (ushort*)(ws + 16 * MB);    // 6 MB  [3072][1024]
    ushort* woh = (ushort*)(ws + 22 * MB);    // 2 MB
    ushort* wol = (ushort*)(ws + 24 * MB);    // 2 MB
    ushort* Qb  = (ushort*)(ws + 26 * MB);    // 8 MB
    ushort* Kb  = (ushort*)(ws + 34 * MB);    // 8 MB
    ushort* Vtb = (ushort*)(ws + 42 * MB);    // 8 MB

    split_x<<<1024, 256, 0, stream>>>(x, xh, MROWS * DMODEL / 4);
    tsplit_w<<<dim3(16, 16, 4), 256, 0, stream>>>(Wq, Wk, Wv, Wo, wtc, woh, wol);

    gemm_qkv<<<dim3(24, 32), 512, 0, stream>>>(xh, wtc, Qb, Kb, Vtb);

    attn<<<dim3(32, 16), 256, 0, stream>>>(Qb, Kb, Vtb, ath, atl);

    gemm_o<<<dim3(16, 32), 512, 0, stream>>>(ath, atl, woh, wol, out);
}

// Round 11
// 127.807 us; speedup vs baseline: 1.4918x; 1.0648x over previous
//
#include <hip/hip_runtime.h>
#include <math.h>

#define BATCH 2
#define SEQ   2048
#define DMODEL 1024
#define NHEAD 16
#define HEADD 64
#define MROWS 4096

typedef __attribute__((ext_vector_type(8))) __bf16 bf16x8;
typedef __attribute__((ext_vector_type(4))) float f32x4;

__device__ __forceinline__ ushort f2bf(float f) {
    uint u = __float_as_uint(f);
    u += 0x7fffu + ((u >> 16) & 1u);
    return (ushort)(u >> 16);
}
__device__ __forceinline__ float bf2f(ushort h) {
    return __uint_as_float(((uint)h) << 16);
}
__device__ __forceinline__ ushort4 pack4bf(float a, float b, float c, float d) {
    union { __bf16 h[4]; ushort4 u; } p;
    p.h[0] = (__bf16)a; p.h[1] = (__bf16)b; p.h[2] = (__bf16)c; p.h[3] = (__bf16)d;
    return p.u;
}
__device__ __forceinline__ float vmax4(const f32x4 v) {
    return fmaxf(fmaxf(v[0], v[1]), fmaxf(v[2], v[3]));
}

#define GLD16(gsrc, ldst)                                                         \
    __builtin_amdgcn_global_load_lds(                                             \
        (const __attribute__((address_space(1))) unsigned int*)(gsrc),            \
        (__attribute__((address_space(3))) unsigned int*)(ldst), 16, 0, 0)

// Q pre-scale: (1/sqrt(64)) * log2(e)  -> softmax in exp2 domain
#define QSCALE 0.1803368801111204f

// ---------------- prep: x fp32 -> bf16 (hi only) ----------------
__global__ __launch_bounds__(256) void split_x(const float* __restrict__ in,
                                               ushort* __restrict__ oh, int n4) {
    int i = blockIdx.x * 256 + threadIdx.x;
    const int stride = gridDim.x * 256;
    for (; i < n4; i += stride) {
        const float4 v = reinterpret_cast<const float4*>(in)[i];
        ushort4 h;
        h.x = f2bf(v.x); h.y = f2bf(v.y); h.z = f2bf(v.z); h.w = f2bf(v.w);
        reinterpret_cast<ushort4*>(oh)[i] = h;
    }
}

// ---------------- prep: W^T; z<3 -> combined QKV hi; z==3 -> Wo hi/lo ----------------
__global__ __launch_bounds__(256) void tsplit_w(const float* __restrict__ Wq,
                                                const float* __restrict__ Wk,
                                                const float* __restrict__ Wv,
                                                const float* __restrict__ Wo,
                                                ushort* __restrict__ wtc,
                                                ushort* __restrict__ woh,
                                                ushort* __restrict__ wol) {
    const int z = blockIdx.z;
    const float* W = (z == 0) ? Wq : (z == 1) ? Wk : (z == 2) ? Wv : Wo;
    __shared__ float T[64][68];
    const int t = threadIdx.x;
    const int k0 = blockIdx.y * 64, n0 = blockIdx.x * 64;
    {
        const int r = t >> 2, c0 = (t & 3) * 16;
        #pragma unroll
        for (int j = 0; j < 4; ++j)
            *reinterpret_cast<float4*>(&T[r][c0 + j * 4]) =
                *reinterpret_cast<const float4*>(&W[(size_t)(k0 + r) * DMODEL + n0 + c0 + j * 4]);
    }
    __syncthreads();
    const int nl = t >> 2, kq = t & 3;
    if (z < 3) {
        ushort hb[16];
        #pragma unroll
        for (int e = 0; e < 16; ++e) hb[e] = f2bf(T[kq * 16 + e][nl]);
        const size_t o = (size_t)(z * 1024 + n0 + nl) * DMODEL + k0 + kq * 16;
        *reinterpret_cast<uint4*>(&wtc[o]) = *reinterpret_cast<uint4*>(&hb[0]);
        *reinterpret_cast<uint4*>(&wtc[o + 8]) = *reinterpret_cast<uint4*>(&hb[8]);
    } else {
        // 2-pass gemm_o only needs Wo hi + A-lo correction; keep hi and lo (lo cheap)
        ushort hb[16];
        #pragma unroll
        for (int e = 0; e < 16; ++e) hb[e] = f2bf(T[kq * 16 + e][nl]);
        const size_t o = (size_t)(n0 + nl) * DMODEL + k0 + kq * 16;
        *reinterpret_cast<uint4*>(&woh[o]) = *reinterpret_cast<uint4*>(&hb[0]);
        *reinterpret_cast<uint4*>(&woh[o + 8]) = *reinterpret_cast<uint4*>(&hb[8]);
        (void)wol;
    }
}

// ---------------- fused QKV GEMM: single-pass bf16, 128x128 tile, BK=64 ----------------
__global__ __launch_bounds__(512) void gemm_qkv(const ushort* __restrict__ xh,
                                                const ushort* __restrict__ wtc,
                                                ushort* __restrict__ Qb,
                                                ushort* __restrict__ Kb,
                                                ushort* __restrict__ Vtb) {
    __shared__ ushort SH[17408];
    ushort* const Ah = SH;
    ushort* const Bh = SH + 8192;

    const int t = threadIdx.x, lane = t & 63, w = t >> 6;
    const int l = lane & 15, g = lane >> 4;
    const int wm = w >> 2, wn = w & 3;
    const int bm = blockIdx.y * 128, bn = blockIdx.x * 128;

    f32x4 acc[4][2];
    #pragma unroll
    for (int mt = 0; mt < 4; ++mt)
        #pragma unroll
        for (int nt = 0; nt < 2; ++nt) acc[mt][nt] = (f32x4){0.f, 0.f, 0.f, 0.f};

    for (int kt = 0; kt < DMODEL; kt += 64) {
        __syncthreads();
        #pragma unroll
        for (int i = 0; i < 4; ++i) {
            const int sid = w * 4 + i;
            const int c = sid & 15;
            const ushort* src = (sid < 16) ? xh : wtc;
            const int rb = (sid < 16) ? bm : bn;
            ushort* dst = ((sid < 16) ? Ah : Bh) + c * 512;
            const int row = c * 8 + (lane >> 3);
            const int sw = ((lane & 7) ^ (row & 7)) << 3;
            GLD16(src + (size_t)(rb + row) * DMODEL + kt + sw, dst);
        }
        __syncthreads();

        bf16x8 af[4][2], bf[2][2];
        #pragma unroll
        for (int mt = 0; mt < 4; ++mt)
            #pragma unroll
            for (int s = 0; s < 2; ++s) {
                const int m = wm * 64 + mt * 16 + l;
                af[mt][s] = *reinterpret_cast<const bf16x8*>(&Ah[m * 64 + (((g + 4 * s) ^ (m & 7)) << 3)]);
            }
        #pragma unroll
        for (int nt = 0; nt < 2; ++nt)
            #pragma unroll
            for (int s = 0; s < 2; ++s) {
                const int n = wn * 32 + nt * 16 + l;
                bf[nt][s] = *reinterpret_cast<const bf16x8*>(&Bh[n * 64 + (((g + 4 * s) ^ (n & 7)) << 3)]);
            }
        __builtin_amdgcn_s_setprio(1);
        #pragma unroll
        for (int mt = 0; mt < 4; ++mt)
            #pragma unroll
            for (int nt = 0; nt < 2; ++nt)
                #pragma unroll
                for (int s = 0; s < 2; ++s)
                    acc[mt][nt] = __builtin_amdgcn_mfma_f32_16x16x32_bf16(af[mt][s], bf[nt][s], acc[mt][nt], 0, 0, 0);
        __builtin_amdgcn_s_setprio(0);
    }

    const int mode = bn >> 10;
    if (mode == 0) {
        #pragma unroll
        for (int mt = 0; mt < 4; ++mt)
            #pragma unroll
            for (int nt = 0; nt < 2; ++nt)
                #pragma unroll
                for (int r = 0; r < 4; ++r) {
                    const int row = bm + wm * 64 + mt * 16 + g * 4 + r;
                    const int col = bn + wn * 32 + nt * 16 + l;
                    Qb[(size_t)row * DMODEL + col] = f2bf(acc[mt][nt][r] * QSCALE);
                }
    } else if (mode == 1) {
        #pragma unroll
        for (int mt = 0; mt < 4; ++mt)
            #pragma unroll
            for (int nt = 0; nt < 2; ++nt)
                #pragma unroll
                for (int r = 0; r < 4; ++r) {
                    const int row = bm + wm * 64 + mt * 16 + g * 4 + r;
                    const int col = (bn - 1024) + wn * 32 + nt * 16 + l;
                    Kb[(size_t)row * DMODEL + col] = f2bf(acc[mt][nt][r]);
                }
    } else {
        __syncthreads();
        ushort* VtL = SH;   // [128 d][136 key]
        #pragma unroll
        for (int mt = 0; mt < 4; ++mt)
            #pragma unroll
            for (int nt = 0; nt < 2; ++nt)
                #pragma unroll
                for (int r = 0; r < 4; ++r) {
                    const int dl = wn * 32 + nt * 16 + l;
                    const int kl = wm * 64 + mt * 16 + g * 4 + r;
                    VtL[dl * 136 + kl] = f2bf(acc[mt][nt][r]);
                }
        __syncthreads();
        const int dl = t >> 2, kq = t & 3;
        const int b = bm >> 11;
        const int row = b * 1024 + (bn - 2048) + dl;
        const int key0 = bm & 2047;
        const size_t o = (size_t)row * SEQ + key0 + kq * 32;
        #pragma unroll
        for (int j = 0; j < 4; ++j)
            *reinterpret_cast<uint4*>(&Vtb[o + j * 8]) =
                *reinterpret_cast<uint4*>(&VtL[dl * 136 + kq * 32 + j * 8]);
    }
}

// ---------------- attention: LDS-staged K/V dbuf, 1 tile/block, 3 blocks/CU ----------------
// Grid (x=bh 32, y=tile 32, heavy-first): XCD-local bh. Block = 256 thr (4 waves),
// wave w owns q-rows [tile*64 + w*16, +16). LDS 41KB -> 3 blocks/CU.
#define LDP 72

__global__ __launch_bounds__(256, 3) void attn(const ushort* __restrict__ Q,
                                               const ushort* __restrict__ K,
                                               const ushort* __restrict__ Vt,
                                               ushort* __restrict__ ATh,
                                               ushort* __restrict__ ATl) {
    __shared__ ushort Kl[2 * 4096];   // [buf][key 64][d 64] swizzled
    __shared__ ushort Vl[2 * 4096];   // [buf][d 64][key 64] swizzled
    __shared__ ushort Pl[64 * LDP];   // [wave*16 + qrow][key]

    const int t = threadIdx.x, lane = t & 63, w = t >> 6;
    const int l = lane & 15, g = lane >> 4;
    const int tile = 31 - blockIdx.y;             // heavy blocks dispatch first
    const int bh = blockIdx.x, b = bh >> 4, h = bh & 15;
    const size_t kbase = (size_t)b * SEQ * DMODEL + h * 64;
    const size_t vbase = (size_t)bh * 64 * SEQ;
    const int q0 = tile * 64 + w * 16;
    const int nch = tile + 1;

    // Q B-operand frags (col=q=lane&15, k=d=32s+8g+e)
    bf16x8 qf[2];
    {
        const size_t qo = (size_t)(b * SEQ + q0 + l) * DMODEL + h * 64 + 8 * g;
        qf[0] = *reinterpret_cast<const bf16x8*>(&Q[qo]);
        qf[1] = *reinterpret_cast<const bf16x8*>(&Q[qo + 32]);
    }

    f32x4 accO[4];
    #pragma unroll
    for (int dt = 0; dt < 4; ++dt) accO[dt] = (f32x4){0.f, 0.f, 0.f, 0.f};
    float m_i = -INFINITY, l_i = 0.f;

    // stage one 64-key chunk into LDS buffer (async, 4 GLD16 per wave)
    auto STAGE = [&](int buf, int kc) {
        const int k0 = kc * 64;
        if (w < 2) {
            #pragma unroll
            for (int i = 0; i < 4; ++i) {
                const int c = w * 4 + i;
                const int row = c * 8 + (lane >> 3);
                const int sw = ((lane & 7) ^ (row & 7)) << 3;
                GLD16(K + kbase + (size_t)(k0 + row) * DMODEL + sw,
                      Kl + buf * 4096 + c * 512);
            }
        } else {
            #pragma unroll
            for (int i = 0; i < 4; ++i) {
                const int c = (w - 2) * 4 + i;
                const int row = c * 8 + (lane >> 3);
                const int sw = ((lane & 7) ^ (row & 7)) << 3;
                GLD16(Vt + vbase + (size_t)row * SEQ + k0 + sw,
                      Vl + buf * 4096 + c * 512);
            }
        }
    };

    auto COMPUTE = [&](int buf, int kc) {
        const int k0 = kc * 64;
        const ushort* Kb_ = Kl + buf * 4096;
        const ushort* Vb_ = Vl + buf * 4096;
        const int xorsw0 = ((g + 0) ^ (l & 7)) << 3;
        const int xorsw1 = ((g + 4) ^ (l & 7)) << 3;

        // K frags from LDS (row=key=16nt+l)
        bf16x8 kf[4][2];
        #pragma unroll
        for (int nt = 0; nt < 4; ++nt) {
            const int ro = (nt * 16 + l) * 64;
            kf[nt][0] = *reinterpret_cast<const bf16x8*>(&Kb_[ro + xorsw0]);
            kf[nt][1] = *reinterpret_cast<const bf16x8*>(&Kb_[ro + xorsw1]);
        }

        // swapped QK^T: sc[nt][r] = score[key=k0+16nt+4g+r][q=q0+l]
        f32x4 sc[4];
        __builtin_amdgcn_s_setprio(1);
        #pragma unroll
        for (int nt = 0; nt < 4; ++nt) {
            f32x4 z = (f32x4){0.f, 0.f, 0.f, 0.f};
            z = __builtin_amdgcn_mfma_f32_16x16x32_bf16(kf[nt][0], qf[0], z, 0, 0, 0);
            z = __builtin_amdgcn_mfma_f32_16x16x32_bf16(kf[nt][1], qf[1], z, 0, 0, 0);
            sc[nt] = z;
        }
        __builtin_amdgcn_s_setprio(0);

        // causal mask on the diagonal chunk
        if (kc == nch - 1) {
            const int qg = q0 + l;
            #pragma unroll
            for (int nt = 0; nt < 4; ++nt)
                #pragma unroll
                for (int r = 0; r < 4; ++r)
                    if (k0 + nt * 16 + g * 4 + r > qg) sc[nt][r] = -INFINITY;
        }

        // online softmax (exp2 domain), tree reductions
        {
            float mc = fmaxf(fmaxf(vmax4(sc[0]), vmax4(sc[1])),
                             fmaxf(vmax4(sc[2]), vmax4(sc[3])));
            mc = fmaxf(mc, __shfl_xor(mc, 16, 64));
            mc = fmaxf(mc, __shfl_xor(mc, 32, 64));

            if (__any(mc > m_i + 8.f)) {              // defer-max rescale
                const float mn = fmaxf(m_i, mc);
                const float al = exp2f(m_i - mn);
                m_i = mn;
                l_i *= al;
                #pragma unroll
                for (int r = 0; r < 4; ++r) {
                    const float ar = __shfl(al, 4 * g + r, 64);
                    #pragma unroll
                    for (int dt = 0; dt < 4; ++dt) accO[dt][r] *= ar;
                }
            }

            float psum[4];
            #pragma unroll
            for (int nt = 0; nt < 4; ++nt) {
                #pragma unroll
                for (int r = 0; r < 4; ++r)
                    sc[nt][r] = exp2f(sc[nt][r] - m_i);
                psum[nt] = (sc[nt][0] + sc[nt][1]) + (sc[nt][2] + sc[nt][3]);
            }
            float rs = (psum[0] + psum[1]) + (psum[2] + psum[3]);
            rs += __shfl_xor(rs, 16, 64);
            rs += __shfl_xor(rs, 32, 64);
            l_i += rs;

            const int prow = w * 16 + l;
            #pragma unroll
            for (int nt = 0; nt < 4; ++nt)
                *reinterpret_cast<ushort4*>(&Pl[prow * LDP + nt * 16 + 4 * g]) =
                    pack4bf(sc[nt][0], sc[nt][1], sc[nt][2], sc[nt][3]);
        }

        // V frags from LDS (row=d=16dt+l) + PV
        bf16x8 vf[4][2];
        #pragma unroll
        for (int dt = 0; dt < 4; ++dt) {
            const int ro = (dt * 16 + l) * 64;
            vf[dt][0] = *reinterpret_cast<const bf16x8*>(&Vb_[ro + xorsw0]);
            vf[dt][1] = *reinterpret_cast<const bf16x8*>(&Vb_[ro + xorsw1]);
        }
        bf16x8 pf[2];
        const int prow = w * 16 + l;
        pf[0] = *reinterpret_cast<const bf16x8*>(&Pl[prow * LDP + 8 * g]);
        pf[1] = *reinterpret_cast<const bf16x8*>(&Pl[prow * LDP + 32 + 8 * g]);
        __builtin_amdgcn_s_setprio(1);
        #pragma unroll
        for (int dt = 0; dt < 4; ++dt) {
            accO[dt] = __builtin_amdgcn_mfma_f32_16x16x32_bf16(pf[0], vf[dt][0], accO[dt], 0, 0, 0);
            accO[dt] = __builtin_amdgcn_mfma_f32_16x16x32_bf16(pf[1], vf[dt][1], accO[dt], 0, 0, 0);
        }
        __builtin_amdgcn_s_setprio(0);
    };

    STAGE(0, 0);
    __syncthreads();

    int cur = 0;
    for (int kc = 0; kc < nch; ++kc) {
        if (kc + 1 < nch) STAGE(cur ^ 1, kc + 1);
        COMPUTE(cur, kc);
        __syncthreads();
        cur ^= 1;
    }

    // epilogue: normalize, emit attended hi/lo bf16
    #pragma unroll
    for (int r = 0; r < 4; ++r) {
        const float lr = __shfl(l_i, 4 * g + r, 64);
        const float inv = 1.f / lr;
        const size_t row = (size_t)(b * SEQ + q0 + g * 4 + r) * DMODEL + h * 64;
        #pragma unroll
        for (int dt = 0; dt < 4; ++dt) {
            const float val = accO[dt][r] * inv;
            const ushort hh = f2bf(val);
            ATh[row + dt * 16 + l] = hh;
            ATl[row + dt * 16 + l] = f2bf(val - bf2f(hh));
        }
    }
}

// ---------------- out GEMM: 2-pass (Ah+Al)·Bh, 128x64 tile, BK=64, fp32 out ----------------
__global__ __launch_bounds__(512) void gemm_o(const ushort* __restrict__ Ahg,
                                              const ushort* __restrict__ Alg,
                                              const ushort* __restrict__ Bhg,
                                              float* __restrict__ C) {
    __shared__ ushort SH[20480];   // Ah 16KB | Al 16KB | Bh 8KB
    ushort* const Ah = SH;
    ushort* const Al = SH + 8192;
    ushort* const Bh = SH + 16384;

    const int t = threadIdx.x, lane = t & 63, w = t >> 6;
    const int l = lane & 15, g = lane >> 4;
    const int wm = w >> 1, wn = w & 1;
    const int bm = blockIdx.y * 128, bn = blockIdx.x * 64;

    f32x4 acc[2][2];
    #pragma unroll
    for (int mt = 0; mt < 2; ++mt)
        #pragma unroll
        for (int nt = 0; nt < 2; ++nt) acc[mt][nt] = (f32x4){0.f, 0.f, 0.f, 0.f};

    for (int kt = 0; kt < DMODEL; kt += 64) {
        __syncthreads();
        #pragma unroll
        for (int i = 0; i < 5; ++i) {
            const int sid = w * 5 + i;            // 0..39
            const ushort* src; ushort* dst; int rb, c;
            if (sid < 16)      { src = Ahg; dst = Ah; rb = bm; c = sid; }
            else if (sid < 32) { src = Alg; dst = Al; rb = bm; c = sid - 16; }
            else               { src = Bhg; dst = Bh; rb = bn; c = sid - 32; }
            const int row = c * 8 + (lane >> 3);
            const int sw = ((lane & 7) ^ (row & 7)) << 3;
            GLD16(src + (size_t)(rb + row) * DMODEL + kt + sw, dst + c * 512);
        }
        __syncthreads();

        bf16x8 ah[2][2], al[2][2], bhf[2][2];
        #pragma unroll
        for (int mt = 0; mt < 2; ++mt)
            #pragma unroll
            for (int s = 0; s < 2; ++s) {
                const int m = wm * 32 + mt * 16 + l;
                const int off = m * 64 + (((g + 4 * s) ^ (m & 7)) << 3);
                ah[mt][s] = *reinterpret_cast<const bf16x8*>(&Ah[off]);
                al[mt][s] = *reinterpret_cast<const bf16x8*>(&Al[off]);
            }
        #pragma unroll
        for (int nt = 0; nt < 2; ++nt)
            #pragma unroll
            for (int s = 0; s < 2; ++s) {
                const int n = wn * 32 + nt * 16 + l;
                const int off = n * 64 + (((g + 4 * s) ^ (n & 7)) << 3);
                bhf[nt][s] = *reinterpret_cast<const bf16x8*>(&Bh[off]);
            }
        __builtin_amdgcn_s_setprio(1);
        #pragma unroll
        for (int mt = 0; mt < 2; ++mt)
            #pragma unroll
            for (int nt = 0; nt < 2; ++nt)
                #pragma unroll
                for (int s = 0; s < 2; ++s) {
                    acc[mt][nt] = __builtin_amdgcn_mfma_f32_16x16x32_bf16(ah[mt][s], bhf[nt][s], acc[mt][nt], 0, 0, 0);
                    acc[mt][nt] = __builtin_amdgcn_mfma_f32_16x16x32_bf16(al[mt][s], bhf[nt][s], acc[mt][nt], 0, 0, 0);
                }
        __builtin_amdgcn_s_setprio(0);
    }

    #pragma unroll
    for (int mt = 0; mt < 2; ++mt)
        #pragma unroll
        for (int nt = 0; nt < 2; ++nt)
            #pragma unroll
            for (int r = 0; r < 4; ++r) {
                const int row = bm + wm * 32 + mt * 16 + g * 4 + r;
                const int col = bn + wn * 32 + nt * 16 + l;
                C[(size_t)row * DMODEL + col] = acc[mt][nt][r];
            }
}

// ---------------- launch ----------------
extern "C" void kernel_launch(void* const* d_in, const int* in_sizes, int n_in,
                              void* d_out, int out_size, void* d_ws, size_t ws_size,
                              hipStream_t stream) {
    const float* x  = (const float*)d_in[0];
    const float* Wq = (const float*)d_in[1];
    const float* Wk = (const float*)d_in[2];
    const float* Wv = (const float*)d_in[3];
    const float* Wo = (const float*)d_in[4];
    float* out = (float*)d_out;

    char* ws = (char*)d_ws;
    const size_t MB = 1024 * 1024;
    ushort* xh  = (ushort*)(ws);              // 8 MB  (aliased as ATh after QKV gemm)
    ushort* ath = xh;
    ushort* atl = (ushort*)(ws + 8 * MB);     // 8 MB
    ushort* wtc = (ushort*)(ws + 16 * MB);    // 6 MB  [3072][1024]
    ushort* woh = (ushort*)(ws + 22 * MB);    // 2 MB
    ushort* wol = (ushort*)(ws + 24 * MB);    // 2 MB (unused)
    ushort* Qb  = (ushort*)(ws + 26 * MB);    // 8 MB
    ushort* Kb  = (ushort*)(ws + 34 * MB);    // 8 MB
    ushort* Vtb = (ushort*)(ws + 42 * MB);    // 8 MB

    split_x<<<1024, 256, 0, stream>>>(x, xh, MROWS * DMODEL / 4);
    tsplit_w<<<dim3(16, 16, 4), 256, 0, stream>>>(Wq, Wk, Wv, Wo, wtc, woh, wol);

    gemm_qkv<<<dim3(24, 32), 512, 0, stream>>>(xh, wtc, Qb, Kb, Vtb);

    attn<<<dim3(32, 32), 256, 0, stream>>>(Qb, Kb, Vtb, ath, atl);

    gemm_o<<<dim3(16, 32), 512, 0, stream>>>(ath, atl, woh, out);
}

// Round 12
// 113.018 us; speedup vs baseline: 1.6870x; 1.1309x over previous
//
#include <hip/hip_runtime.h>
#include <math.h>

#define BATCH 2
#define SEQ   2048
#define DMODEL 1024
#define NHEAD 16
#define HEADD 64
#define MROWS 4096

typedef __attribute__((ext_vector_type(8))) __bf16 bf16x8;
typedef __attribute__((ext_vector_type(4))) float f32x4;

__device__ __forceinline__ ushort f2bf(float f) {
    uint u = __float_as_uint(f);
    u += 0x7fffu + ((u >> 16) & 1u);
    return (ushort)(u >> 16);
}
__device__ __forceinline__ float bf2f(ushort h) {
    return __uint_as_float(((uint)h) << 16);
}
__device__ __forceinline__ ushort4 pack4bf(float a, float b, float c, float d) {
    union { __bf16 h[4]; ushort4 u; } p;
    p.h[0] = (__bf16)a; p.h[1] = (__bf16)b; p.h[2] = (__bf16)c; p.h[3] = (__bf16)d;
    return p.u;
}
__device__ __forceinline__ float vmax4(const f32x4 v) {
    return fmaxf(fmaxf(v[0], v[1]), fmaxf(v[2], v[3]));
}

#define GLD16(gsrc, ldst)                                                         \
    __builtin_amdgcn_global_load_lds(                                             \
        (const __attribute__((address_space(1))) unsigned int*)(gsrc),            \
        (__attribute__((address_space(3))) unsigned int*)(ldst), 16, 0, 0)

// Q pre-scale: (1/sqrt(64)) * log2(e)  -> softmax in exp2 domain
#define QSCALE 0.1803368801111204f

// ---------------- merged prep: z<3 -> W^T->wtc; z==3 -> Wo^T->woh; z==4 -> x split ----------------
__global__ __launch_bounds__(256) void prep(const float* __restrict__ x,
                                            const float* __restrict__ Wq,
                                            const float* __restrict__ Wk,
                                            const float* __restrict__ Wv,
                                            const float* __restrict__ Wo,
                                            ushort* __restrict__ wtc,
                                            ushort* __restrict__ woh,
                                            ushort* __restrict__ xh) {
    const int z = blockIdx.z;
    const int t = threadIdx.x;
    if (z == 4) {
        // x fp32 -> bf16, grid-stride over 1M float4 with 256 blocks
        const int n4 = MROWS * DMODEL / 4;
        int i = (blockIdx.y * 16 + blockIdx.x) * 256 + t;
        const int stride = 256 * 256;
        for (; i < n4; i += stride) {
            const float4 v = reinterpret_cast<const float4*>(x)[i];
            ushort4 h;
            h.x = f2bf(v.x); h.y = f2bf(v.y); h.z = f2bf(v.z); h.w = f2bf(v.w);
            reinterpret_cast<ushort4*>(xh)[i] = h;
        }
        return;
    }
    const float* W = (z == 0) ? Wq : (z == 1) ? Wk : (z == 2) ? Wv : Wo;
    __shared__ float T[64][68];
    const int k0 = blockIdx.y * 64, n0 = blockIdx.x * 64;
    {
        const int r = t >> 2, c0 = (t & 3) * 16;
        #pragma unroll
        for (int j = 0; j < 4; ++j)
            *reinterpret_cast<float4*>(&T[r][c0 + j * 4]) =
                *reinterpret_cast<const float4*>(&W[(size_t)(k0 + r) * DMODEL + n0 + c0 + j * 4]);
    }
    __syncthreads();
    const int nl = t >> 2, kq = t & 3;
    ushort hb[16];
    #pragma unroll
    for (int e = 0; e < 16; ++e) hb[e] = f2bf(T[kq * 16 + e][nl]);
    if (z < 3) {
        const size_t o = (size_t)(z * 1024 + n0 + nl) * DMODEL + k0 + kq * 16;
        *reinterpret_cast<uint4*>(&wtc[o]) = *reinterpret_cast<uint4*>(&hb[0]);
        *reinterpret_cast<uint4*>(&wtc[o + 8]) = *reinterpret_cast<uint4*>(&hb[8]);
    } else {
        const size_t o = (size_t)(n0 + nl) * DMODEL + k0 + kq * 16;
        *reinterpret_cast<uint4*>(&woh[o]) = *reinterpret_cast<uint4*>(&hb[0]);
        *reinterpret_cast<uint4*>(&woh[o + 8]) = *reinterpret_cast<uint4*>(&hb[8]);
    }
}

// ---------------- fused QKV GEMM: single-pass bf16, 128x128 tile, BK=64 ----------------
__global__ __launch_bounds__(512) void gemm_qkv(const ushort* __restrict__ xh,
                                                const ushort* __restrict__ wtc,
                                                ushort* __restrict__ Qb,
                                                ushort* __restrict__ Kb,
                                                ushort* __restrict__ Vtb) {
    __shared__ ushort SH[17408];
    ushort* const Ah = SH;
    ushort* const Bh = SH + 8192;

    const int t = threadIdx.x, lane = t & 63, w = t >> 6;
    const int l = lane & 15, g = lane >> 4;
    const int wm = w >> 2, wn = w & 3;
    const int bm = blockIdx.y * 128, bn = blockIdx.x * 128;

    f32x4 acc[4][2];
    #pragma unroll
    for (int mt = 0; mt < 4; ++mt)
        #pragma unroll
        for (int nt = 0; nt < 2; ++nt) acc[mt][nt] = (f32x4){0.f, 0.f, 0.f, 0.f};

    for (int kt = 0; kt < DMODEL; kt += 64) {
        __syncthreads();
        #pragma unroll
        for (int i = 0; i < 4; ++i) {
            const int sid = w * 4 + i;
            const int c = sid & 15;
            const ushort* src = (sid < 16) ? xh : wtc;
            const int rb = (sid < 16) ? bm : bn;
            ushort* dst = ((sid < 16) ? Ah : Bh) + c * 512;
            const int row = c * 8 + (lane >> 3);
            const int sw = ((lane & 7) ^ (row & 7)) << 3;
            GLD16(src + (size_t)(rb + row) * DMODEL + kt + sw, dst);
        }
        __syncthreads();

        bf16x8 af[4][2], bf[2][2];
        #pragma unroll
        for (int mt = 0; mt < 4; ++mt)
            #pragma unroll
            for (int s = 0; s < 2; ++s) {
                const int m = wm * 64 + mt * 16 + l;
                af[mt][s] = *reinterpret_cast<const bf16x8*>(&Ah[m * 64 + (((g + 4 * s) ^ (m & 7)) << 3)]);
            }
        #pragma unroll
        for (int nt = 0; nt < 2; ++nt)
            #pragma unroll
            for (int s = 0; s < 2; ++s) {
                const int n = wn * 32 + nt * 16 + l;
                bf[nt][s] = *reinterpret_cast<const bf16x8*>(&Bh[n * 64 + (((g + 4 * s) ^ (n & 7)) << 3)]);
            }
        __builtin_amdgcn_s_setprio(1);
        #pragma unroll
        for (int mt = 0; mt < 4; ++mt)
            #pragma unroll
            for (int nt = 0; nt < 2; ++nt)
                #pragma unroll
                for (int s = 0; s < 2; ++s)
                    acc[mt][nt] = __builtin_amdgcn_mfma_f32_16x16x32_bf16(af[mt][s], bf[nt][s], acc[mt][nt], 0, 0, 0);
        __builtin_amdgcn_s_setprio(0);
    }

    const int mode = bn >> 10;
    if (mode == 0) {
        #pragma unroll
        for (int mt = 0; mt < 4; ++mt)
            #pragma unroll
            for (int nt = 0; nt < 2; ++nt)
                #pragma unroll
                for (int r = 0; r < 4; ++r) {
                    const int row = bm + wm * 64 + mt * 16 + g * 4 + r;
                    const int col = bn + wn * 32 + nt * 16 + l;
                    Qb[(size_t)row * DMODEL + col] = f2bf(acc[mt][nt][r] * QSCALE);
                }
    } else if (mode == 1) {
        #pragma unroll
        for (int mt = 0; mt < 4; ++mt)
            #pragma unroll
            for (int nt = 0; nt < 2; ++nt)
                #pragma unroll
                for (int r = 0; r < 4; ++r) {
                    const int row = bm + wm * 64 + mt * 16 + g * 4 + r;
                    const int col = (bn - 1024) + wn * 32 + nt * 16 + l;
                    Kb[(size_t)row * DMODEL + col] = f2bf(acc[mt][nt][r]);
                }
    } else {
        __syncthreads();
        ushort* VtL = SH;   // [128 d][136 key]
        #pragma unroll
        for (int mt = 0; mt < 4; ++mt)
            #pragma unroll
            for (int nt = 0; nt < 2; ++nt)
                #pragma unroll
                for (int r = 0; r < 4; ++r) {
                    const int dl = wn * 32 + nt * 16 + l;
                    const int kl = wm * 64 + mt * 16 + g * 4 + r;
                    VtL[dl * 136 + kl] = f2bf(acc[mt][nt][r]);
                }
        __syncthreads();
        const int dl = t >> 2, kq = t & 3;
        const int b = bm >> 11;
        const int row = b * 1024 + (bn - 2048) + dl;
        const int key0 = bm & 2047;
        const size_t o = (size_t)row * SEQ + key0 + kq * 32;
        #pragma unroll
        for (int j = 0; j < 4; ++j)
            *reinterpret_cast<uint4*>(&Vtb[o + j * 8]) =
                *reinterpret_cast<uint4*>(&VtL[dl * 136 + kq * 32 + j * 8]);
    }
}

// ---------------- attention: LDS-staged K/V dbuf, 1 tile/block, 3 blocks/CU ----------------
#define LDP 72

__global__ __launch_bounds__(256, 3) void attn(const ushort* __restrict__ Q,
                                               const ushort* __restrict__ K,
                                               const ushort* __restrict__ Vt,
                                               ushort* __restrict__ ATh) {
    __shared__ ushort Kl[2 * 4096];   // [buf][key 64][d 64] swizzled
    __shared__ ushort Vl[2 * 4096];   // [buf][d 64][key 64] swizzled
    __shared__ ushort Pl[64 * LDP];   // [wave*16 + qrow][key]

    const int t = threadIdx.x, lane = t & 63, w = t >> 6;
    const int l = lane & 15, g = lane >> 4;
    const int tile = 31 - blockIdx.y;             // heavy blocks dispatch first
    const int bh = blockIdx.x, b = bh >> 4, h = bh & 15;
    const size_t kbase = (size_t)b * SEQ * DMODEL + h * 64;
    const size_t vbase = (size_t)bh * 64 * SEQ;
    const int q0 = tile * 64 + w * 16;
    const int nch = tile + 1;

    // Q B-operand frags (col=q=lane&15, k=d=32s+8g+e)
    bf16x8 qf[2];
    {
        const size_t qo = (size_t)(b * SEQ + q0 + l) * DMODEL + h * 64 + 8 * g;
        qf[0] = *reinterpret_cast<const bf16x8*>(&Q[qo]);
        qf[1] = *reinterpret_cast<const bf16x8*>(&Q[qo + 32]);
    }

    f32x4 accO[4];
    #pragma unroll
    for (int dt = 0; dt < 4; ++dt) accO[dt] = (f32x4){0.f, 0.f, 0.f, 0.f};
    float m_i = -INFINITY, l_i = 0.f;

    auto STAGE = [&](int buf, int kc) {
        const int k0 = kc * 64;
        if (w < 2) {
            #pragma unroll
            for (int i = 0; i < 4; ++i) {
                const int c = w * 4 + i;
                const int row = c * 8 + (lane >> 3);
                const int sw = ((lane & 7) ^ (row & 7)) << 3;
                GLD16(K + kbase + (size_t)(k0 + row) * DMODEL + sw,
                      Kl + buf * 4096 + c * 512);
            }
        } else {
            #pragma unroll
            for (int i = 0; i < 4; ++i) {
                const int c = (w - 2) * 4 + i;
                const int row = c * 8 + (lane >> 3);
                const int sw = ((lane & 7) ^ (row & 7)) << 3;
                GLD16(Vt + vbase + (size_t)row * SEQ + k0 + sw,
                      Vl + buf * 4096 + c * 512);
            }
        }
    };

    auto COMPUTE = [&](int buf, int kc) {
        const int k0 = kc * 64;
        const ushort* Kb_ = Kl + buf * 4096;
        const ushort* Vb_ = Vl + buf * 4096;
        const int xorsw0 = ((g + 0) ^ (l & 7)) << 3;
        const int xorsw1 = ((g + 4) ^ (l & 7)) << 3;

        bf16x8 kf[4][2];
        #pragma unroll
        for (int nt = 0; nt < 4; ++nt) {
            const int ro = (nt * 16 + l) * 64;
            kf[nt][0] = *reinterpret_cast<const bf16x8*>(&Kb_[ro + xorsw0]);
            kf[nt][1] = *reinterpret_cast<const bf16x8*>(&Kb_[ro + xorsw1]);
        }

        f32x4 sc[4];
        __builtin_amdgcn_s_setprio(1);
        #pragma unroll
        for (int nt = 0; nt < 4; ++nt) {
            f32x4 z = (f32x4){0.f, 0.f, 0.f, 0.f};
            z = __builtin_amdgcn_mfma_f32_16x16x32_bf16(kf[nt][0], qf[0], z, 0, 0, 0);
            z = __builtin_amdgcn_mfma_f32_16x16x32_bf16(kf[nt][1], qf[1], z, 0, 0, 0);
            sc[nt] = z;
        }
        __builtin_amdgcn_s_setprio(0);

        if (kc == nch - 1) {
            const int qg = q0 + l;
            #pragma unroll
            for (int nt = 0; nt < 4; ++nt)
                #pragma unroll
                for (int r = 0; r < 4; ++r)
                    if (k0 + nt * 16 + g * 4 + r > qg) sc[nt][r] = -INFINITY;
        }

        {
            float mc = fmaxf(fmaxf(vmax4(sc[0]), vmax4(sc[1])),
                             fmaxf(vmax4(sc[2]), vmax4(sc[3])));
            mc = fmaxf(mc, __shfl_xor(mc, 16, 64));
            mc = fmaxf(mc, __shfl_xor(mc, 32, 64));

            if (__any(mc > m_i + 8.f)) {              // defer-max rescale
                const float mn = fmaxf(m_i, mc);
                const float al = exp2f(m_i - mn);
                m_i = mn;
                l_i *= al;
                #pragma unroll
                for (int r = 0; r < 4; ++r) {
                    const float ar = __shfl(al, 4 * g + r, 64);
                    #pragma unroll
                    for (int dt = 0; dt < 4; ++dt) accO[dt][r] *= ar;
                }
            }

            float psum[4];
            #pragma unroll
            for (int nt = 0; nt < 4; ++nt) {
                #pragma unroll
                for (int r = 0; r < 4; ++r)
                    sc[nt][r] = exp2f(sc[nt][r] - m_i);
                psum[nt] = (sc[nt][0] + sc[nt][1]) + (sc[nt][2] + sc[nt][3]);
            }
            float rs = (psum[0] + psum[1]) + (psum[2] + psum[3]);
            rs += __shfl_xor(rs, 16, 64);
            rs += __shfl_xor(rs, 32, 64);
            l_i += rs;

            const int prow = w * 16 + l;
            #pragma unroll
            for (int nt = 0; nt < 4; ++nt)
                *reinterpret_cast<ushort4*>(&Pl[prow * LDP + nt * 16 + 4 * g]) =
                    pack4bf(sc[nt][0], sc[nt][1], sc[nt][2], sc[nt][3]);
        }

        bf16x8 vf[4][2];
        #pragma unroll
        for (int dt = 0; dt < 4; ++dt) {
            const int ro = (dt * 16 + l) * 64;
            vf[dt][0] = *reinterpret_cast<const bf16x8*>(&Vb_[ro + xorsw0]);
            vf[dt][1] = *reinterpret_cast<const bf16x8*>(&Vb_[ro + xorsw1]);
        }
        bf16x8 pf[2];
        const int prow = w * 16 + l;
        pf[0] = *reinterpret_cast<const bf16x8*>(&Pl[prow * LDP + 8 * g]);
        pf[1] = *reinterpret_cast<const bf16x8*>(&Pl[prow * LDP + 32 + 8 * g]);
        __builtin_amdgcn_s_setprio(1);
        #pragma unroll
        for (int dt = 0; dt < 4; ++dt) {
            accO[dt] = __builtin_amdgcn_mfma_f32_16x16x32_bf16(pf[0], vf[dt][0], accO[dt], 0, 0, 0);
            accO[dt] = __builtin_amdgcn_mfma_f32_16x16x32_bf16(pf[1], vf[dt][1], accO[dt], 0, 0, 0);
        }
        __builtin_amdgcn_s_setprio(0);
    };

    STAGE(0, 0);
    __syncthreads();

    int cur = 0;
    for (int kc = 0; kc < nch; ++kc) {
        if (kc + 1 < nch) STAGE(cur ^ 1, kc + 1);
        COMPUTE(cur, kc);
        __syncthreads();
        cur ^= 1;
    }

    // epilogue: normalize, emit attended bf16 (hi only)
    #pragma unroll
    for (int r = 0; r < 4; ++r) {
        const float lr = __shfl(l_i, 4 * g + r, 64);
        const float inv = 1.f / lr;
        const size_t row = (size_t)(b * SEQ + q0 + g * 4 + r) * DMODEL + h * 64;
        #pragma unroll
        for (int dt = 0; dt < 4; ++dt)
            ATh[row + dt * 16 + l] = f2bf(accO[dt][r] * inv);
    }
}

// ---------------- out GEMM: single-pass Ah·Bh, 128x64 tile, BK=64, fp32 out ----------------
__global__ __launch_bounds__(512) void gemm_o(const ushort* __restrict__ Ahg,
                                              const ushort* __restrict__ Bhg,
                                              float* __restrict__ C) {
    __shared__ ushort SH[12288];   // Ah 16KB | Bh 8KB
    ushort* const Ah = SH;
    ushort* const Bh = SH + 8192;

    const int t = threadIdx.x, lane = t & 63, w = t >> 6;
    const int l = lane & 15, g = lane >> 4;
    const int wm = w >> 1, wn = w & 1;
    const int bm = blockIdx.y * 128, bn = blockIdx.x * 64;

    f32x4 acc[2][2];
    #pragma unroll
    for (int mt = 0; mt < 2; ++mt)
        #pragma unroll
        for (int nt = 0; nt < 2; ++nt) acc[mt][nt] = (f32x4){0.f, 0.f, 0.f, 0.f};

    for (int kt = 0; kt < DMODEL; kt += 64) {
        __syncthreads();
        #pragma unroll
        for (int i = 0; i < 3; ++i) {
            const int sid = w * 3 + i;            // 0..23
            const ushort* src; ushort* dst; int rb, c;
            if (sid < 16) { src = Ahg; dst = Ah; rb = bm; c = sid; }
            else          { src = Bhg; dst = Bh; rb = bn; c = sid - 16; }
            const int row = c * 8 + (lane >> 3);
            const int sw = ((lane & 7) ^ (row & 7)) << 3;
            GLD16(src + (size_t)(rb + row) * DMODEL + kt + sw, dst + c * 512);
        }
        __syncthreads();

        bf16x8 ah[2][2], bhf[2][2];
        #pragma unroll
        for (int mt = 0; mt < 2; ++mt)
            #pragma unroll
            for (int s = 0; s < 2; ++s) {
                const int m = wm * 32 + mt * 16 + l;
                ah[mt][s] = *reinterpret_cast<const bf16x8*>(&Ah[m * 64 + (((g + 4 * s) ^ (m & 7)) << 3)]);
            }
        #pragma unroll
        for (int nt = 0; nt < 2; ++nt)
            #pragma unroll
            for (int s = 0; s < 2; ++s) {
                const int n = wn * 32 + nt * 16 + l;
                bhf[nt][s] = *reinterpret_cast<const bf16x8*>(&Bh[n * 64 + (((g + 4 * s) ^ (n & 7)) << 3)]);
            }
        __builtin_amdgcn_s_setprio(1);
        #pragma unroll
        for (int mt = 0; mt < 2; ++mt)
            #pragma unroll
            for (int nt = 0; nt < 2; ++nt)
                #pragma unroll
                for (int s = 0; s < 2; ++s)
                    acc[mt][nt] = __builtin_amdgcn_mfma_f32_16x16x32_bf16(ah[mt][s], bhf[nt][s], acc[mt][nt], 0, 0, 0);
        __builtin_amdgcn_s_setprio(0);
    }

    #pragma unroll
    for (int mt = 0; mt < 2; ++mt)
        #pragma unroll
        for (int nt = 0; nt < 2; ++nt)
            #pragma unroll
            for (int r = 0; r < 4; ++r) {
                const int row = bm + wm * 32 + mt * 16 + g * 4 + r;
                const int col = bn + wn * 32 + nt * 16 + l;
                C[(size_t)row * DMODEL + col] = acc[mt][nt][r];
            }
}

// ---------------- launch ----------------
extern "C" void kernel_launch(void* const* d_in, const int* in_sizes, int n_in,
                              void* d_out, int out_size, void* d_ws, size_t ws_size,
                              hipStream_t stream) {
    const float* x  = (const float*)d_in[0];
    const float* Wq = (const float*)d_in[1];
    const float* Wk = (const float*)d_in[2];
    const float* Wv = (const float*)d_in[3];
    const float* Wo = (const float*)d_in[4];
    float* out = (float*)d_out;

    char* ws = (char*)d_ws;
    const size_t MB = 1024 * 1024;
    ushort* xh  = (ushort*)(ws);              // 8 MB (aliased as ATh after QKV gemm)
    ushort* ath = xh;
    ushort* wtc = (ushort*)(ws + 16 * MB);    // 6 MB  [3072][1024]
    ushort* woh = (ushort*)(ws + 22 * MB);    // 2 MB
    ushort* Qb  = (ushort*)(ws + 26 * MB);    // 8 MB
    ushort* Kb  = (ushort*)(ws + 34 * MB);    // 8 MB
    ushort* Vtb = (ushort*)(ws + 42 * MB);    // 8 MB

    prep<<<dim3(16, 16, 5), 256, 0, stream>>>(x, Wq, Wk, Wv, Wo, wtc, woh, xh);

    gemm_qkv<<<dim3(24, 32), 512, 0, stream>>>(xh, wtc, Qb, Kb, Vtb);

    attn<<<dim3(32, 32), 256, 0, stream>>>(Qb, Kb, Vtb, ath);

    gemm_o<<<dim3(16, 32), 512, 0, stream>>>(ath, woh, out);
}

// Round 13
// 110.302 us; speedup vs baseline: 1.7285x; 1.0246x over previous
//
#include <hip/hip_runtime.h>
#include <math.h>

#define BATCH 2
#define SEQ   2048
#define DMODEL 1024
#define NHEAD 16
#define HEADD 64
#define MROWS 4096

typedef __attribute__((ext_vector_type(8))) __bf16 bf16x8;
typedef __attribute__((ext_vector_type(4))) float f32x4;

__device__ __forceinline__ ushort f2bf(float f) {
    uint u = __float_as_uint(f);
    u += 0x7fffu + ((u >> 16) & 1u);
    return (ushort)(u >> 16);
}
__device__ __forceinline__ float bf2f(ushort h) {
    return __uint_as_float(((uint)h) << 16);
}
__device__ __forceinline__ ushort4 pack4bf(float a, float b, float c, float d) {
    union { __bf16 h[4]; ushort4 u; } p;
    p.h[0] = (__bf16)a; p.h[1] = (__bf16)b; p.h[2] = (__bf16)c; p.h[3] = (__bf16)d;
    return p.u;
}
__device__ __forceinline__ float vmax4(const f32x4 v) {
    return fmaxf(fmaxf(v[0], v[1]), fmaxf(v[2], v[3]));
}

#define GLD16(gsrc, ldst)                                                         \
    __builtin_amdgcn_global_load_lds(                                             \
        (const __attribute__((address_space(1))) unsigned int*)(gsrc),            \
        (__attribute__((address_space(3))) unsigned int*)(ldst), 16, 0, 0)

// Q pre-scale: (1/sqrt(64)) * log2(e)  -> softmax in exp2 domain
#define QSCALE 0.1803368801111204f

// ---------------- merged prep: z<3 -> W^T->wtc; z==3 -> Wo^T->woh; z==4 -> x split ----------------
__global__ __launch_bounds__(256) void prep(const float* __restrict__ x,
                                            const float* __restrict__ Wq,
                                            const float* __restrict__ Wk,
                                            const float* __restrict__ Wv,
                                            const float* __restrict__ Wo,
                                            ushort* __restrict__ wtc,
                                            ushort* __restrict__ woh,
                                            ushort* __restrict__ xh) {
    const int z = blockIdx.z;
    const int t = threadIdx.x;
    if (z == 4) {
        const int n4 = MROWS * DMODEL / 4;
        int i = (blockIdx.y * 16 + blockIdx.x) * 256 + t;
        const int stride = 256 * 256;
        for (; i < n4; i += stride) {
            const float4 v = reinterpret_cast<const float4*>(x)[i];
            ushort4 h;
            h.x = f2bf(v.x); h.y = f2bf(v.y); h.z = f2bf(v.z); h.w = f2bf(v.w);
            reinterpret_cast<ushort4*>(xh)[i] = h;
        }
        return;
    }
    const float* W = (z == 0) ? Wq : (z == 1) ? Wk : (z == 2) ? Wv : Wo;
    __shared__ float T[64][68];
    const int k0 = blockIdx.y * 64, n0 = blockIdx.x * 64;
    {
        const int r = t >> 2, c0 = (t & 3) * 16;
        #pragma unroll
        for (int j = 0; j < 4; ++j)
            *reinterpret_cast<float4*>(&T[r][c0 + j * 4]) =
                *reinterpret_cast<const float4*>(&W[(size_t)(k0 + r) * DMODEL + n0 + c0 + j * 4]);
    }
    __syncthreads();
    const int nl = t >> 2, kq = t & 3;
    ushort hb[16];
    #pragma unroll
    for (int e = 0; e < 16; ++e) hb[e] = f2bf(T[kq * 16 + e][nl]);
    if (z < 3) {
        const size_t o = (size_t)(z * 1024 + n0 + nl) * DMODEL + k0 + kq * 16;
        *reinterpret_cast<uint4*>(&wtc[o]) = *reinterpret_cast<uint4*>(&hb[0]);
        *reinterpret_cast<uint4*>(&wtc[o + 8]) = *reinterpret_cast<uint4*>(&hb[8]);
    } else {
        const size_t o = (size_t)(n0 + nl) * DMODEL + k0 + kq * 16;
        *reinterpret_cast<uint4*>(&woh[o]) = *reinterpret_cast<uint4*>(&hb[0]);
        *reinterpret_cast<uint4*>(&woh[o + 8]) = *reinterpret_cast<uint4*>(&hb[8]);
    }
}

// ---------------- fused QKV GEMM: 128x128 tile, BK=64, 256 thr, wave-tile 64x64 ----------------
// MFMA:ds_read ratio 32:16 per wave-K-step (was 8:12) -> DS pipe no longer the cap.
__global__ __launch_bounds__(256, 3) void gemm_qkv(const ushort* __restrict__ xh,
                                                   const ushort* __restrict__ wtc,
                                                   ushort* __restrict__ Qb,
                                                   ushort* __restrict__ Kb,
                                                   ushort* __restrict__ Vtb) {
    __shared__ ushort SH[17408];   // Ah 16KB | Bh 16KB ; epilogue reuse VtL 128x136
    ushort* const Ah = SH;
    ushort* const Bh = SH + 8192;

    const int t = threadIdx.x, lane = t & 63, w = t >> 6;   // w 0..3
    const int l = lane & 15, g = lane >> 4;
    const int wm = w >> 1, wn = w & 1;                      // 2x2 wave grid
    const int bm = blockIdx.y * 128, bn = blockIdx.x * 128;

    f32x4 acc[4][4];
    #pragma unroll
    for (int mt = 0; mt < 4; ++mt)
        #pragma unroll
        for (int nt = 0; nt < 4; ++nt) acc[mt][nt] = (f32x4){0.f, 0.f, 0.f, 0.f};

    for (int kt = 0; kt < DMODEL; kt += 64) {
        __syncthreads();
        #pragma unroll
        for (int i = 0; i < 8; ++i) {
            const int sid = w * 8 + i;            // 0..31
            const int c = sid & 15;
            const ushort* src = (sid < 16) ? xh : wtc;
            const int rb = (sid < 16) ? bm : bn;
            ushort* dst = ((sid < 16) ? Ah : Bh) + c * 512;
            const int row = c * 8 + (lane >> 3);
            const int sw = ((lane & 7) ^ (row & 7)) << 3;
            GLD16(src + (size_t)(rb + row) * DMODEL + kt + sw, dst);
        }
        __syncthreads();

        bf16x8 af[4][2], bf[4][2];
        #pragma unroll
        for (int mt = 0; mt < 4; ++mt)
            #pragma unroll
            for (int s = 0; s < 2; ++s) {
                const int m = wm * 64 + mt * 16 + l;
                af[mt][s] = *reinterpret_cast<const bf16x8*>(&Ah[m * 64 + (((g + 4 * s) ^ (m & 7)) << 3)]);
            }
        #pragma unroll
        for (int nt = 0; nt < 4; ++nt)
            #pragma unroll
            for (int s = 0; s < 2; ++s) {
                const int n = wn * 64 + nt * 16 + l;
                bf[nt][s] = *reinterpret_cast<const bf16x8*>(&Bh[n * 64 + (((g + 4 * s) ^ (n & 7)) << 3)]);
            }
        __builtin_amdgcn_s_setprio(1);
        #pragma unroll
        for (int mt = 0; mt < 4; ++mt)
            #pragma unroll
            for (int nt = 0; nt < 4; ++nt)
                #pragma unroll
                for (int s = 0; s < 2; ++s)
                    acc[mt][nt] = __builtin_amdgcn_mfma_f32_16x16x32_bf16(af[mt][s], bf[nt][s], acc[mt][nt], 0, 0, 0);
        __builtin_amdgcn_s_setprio(0);
    }

    const int mode = bn >> 10;
    if (mode == 0) {
        #pragma unroll
        for (int mt = 0; mt < 4; ++mt)
            #pragma unroll
            for (int nt = 0; nt < 4; ++nt)
                #pragma unroll
                for (int r = 0; r < 4; ++r) {
                    const int row = bm + wm * 64 + mt * 16 + g * 4 + r;
                    const int col = bn + wn * 64 + nt * 16 + l;
                    Qb[(size_t)row * DMODEL + col] = f2bf(acc[mt][nt][r] * QSCALE);
                }
    } else if (mode == 1) {
        #pragma unroll
        for (int mt = 0; mt < 4; ++mt)
            #pragma unroll
            for (int nt = 0; nt < 4; ++nt)
                #pragma unroll
                for (int r = 0; r < 4; ++r) {
                    const int row = bm + wm * 64 + mt * 16 + g * 4 + r;
                    const int col = (bn - 1024) + wn * 64 + nt * 16 + l;
                    Kb[(size_t)row * DMODEL + col] = f2bf(acc[mt][nt][r]);
                }
    } else {
        __syncthreads();
        ushort* VtL = SH;   // [128 d][136 key]
        #pragma unroll
        for (int mt = 0; mt < 4; ++mt)
            #pragma unroll
            for (int nt = 0; nt < 4; ++nt)
                #pragma unroll
                for (int r = 0; r < 4; ++r) {
                    const int dl = wn * 64 + nt * 16 + l;
                    const int kl = wm * 64 + mt * 16 + g * 4 + r;
                    VtL[dl * 136 + kl] = f2bf(acc[mt][nt][r]);
                }
        __syncthreads();
        const int dl = t >> 1, kq = t & 1;        // 128 rows, 2 threads/row
        const int b = bm >> 11;
        const int row = b * 1024 + (bn - 2048) + dl;
        const int key0 = bm & 2047;
        const size_t o = (size_t)row * SEQ + key0 + kq * 64;
        #pragma unroll
        for (int j = 0; j < 8; ++j)               // 8 x uint4 = 64 keys/thread
            *reinterpret_cast<uint4*>(&Vtb[o + j * 8]) =
                *reinterpret_cast<uint4*>(&VtL[dl * 136 + kq * 64 + j * 8]);
    }
}

// ---------------- attention: LDS-staged K/V dbuf, swizzled P, 4 blocks/CU ----------------
__global__ __launch_bounds__(256, 4) void attn(const ushort* __restrict__ Q,
                                               const ushort* __restrict__ K,
                                               const ushort* __restrict__ Vt,
                                               ushort* __restrict__ ATh) {
    __shared__ ushort Kl[2 * 4096];   // [buf][key 64][d 64] swizzled   16KB
    __shared__ ushort Vl[2 * 4096];   // [buf][d 64][key 64] swizzled   16KB
    __shared__ ushort Pl[4096];       // [64 q][64 key] XOR-swizzled     8KB  -> 40KB total

    const int t = threadIdx.x, lane = t & 63, w = t >> 6;
    const int l = lane & 15, g = lane >> 4;
    const int tile = 31 - blockIdx.y;             // heavy blocks dispatch first
    const int bh = blockIdx.x, b = bh >> 4, h = bh & 15;
    const size_t kbase = (size_t)b * SEQ * DMODEL + h * 64;
    const size_t vbase = (size_t)bh * 64 * SEQ;
    const int q0 = tile * 64 + w * 16;
    const int nch = tile + 1;

    // Q B-operand frags (col=q=lane&15, k=d=32s+8g+e)
    bf16x8 qf[2];
    {
        const size_t qo = (size_t)(b * SEQ + q0 + l) * DMODEL + h * 64 + 8 * g;
        qf[0] = *reinterpret_cast<const bf16x8*>(&Q[qo]);
        qf[1] = *reinterpret_cast<const bf16x8*>(&Q[qo + 32]);
    }

    f32x4 accO[4];
    #pragma unroll
    for (int dt = 0; dt < 4; ++dt) accO[dt] = (f32x4){0.f, 0.f, 0.f, 0.f};
    float m_i = -INFINITY, l_i = 0.f;

    auto STAGE = [&](int buf, int kc) {
        const int k0 = kc * 64;
        if (w < 2) {
            #pragma unroll
            for (int i = 0; i < 4; ++i) {
                const int c = w * 4 + i;
                const int row = c * 8 + (lane >> 3);
                const int sw = ((lane & 7) ^ (row & 7)) << 3;
                GLD16(K + kbase + (size_t)(k0 + row) * DMODEL + sw,
                      Kl + buf * 4096 + c * 512);
            }
        } else {
            #pragma unroll
            for (int i = 0; i < 4; ++i) {
                const int c = (w - 2) * 4 + i;
                const int row = c * 8 + (lane >> 3);
                const int sw = ((lane & 7) ^ (row & 7)) << 3;
                GLD16(Vt + vbase + (size_t)row * SEQ + k0 + sw,
                      Vl + buf * 4096 + c * 512);
            }
        }
    };

    auto COMPUTE = [&](int buf, int kc) {
        const int k0 = kc * 64;
        const ushort* Kb_ = Kl + buf * 4096;
        const ushort* Vb_ = Vl + buf * 4096;
        const int xorsw0 = ((g + 0) ^ (l & 7)) << 3;
        const int xorsw1 = ((g + 4) ^ (l & 7)) << 3;

        bf16x8 kf[4][2];
        #pragma unroll
        for (int nt = 0; nt < 4; ++nt) {
            const int ro = (nt * 16 + l) * 64;
            kf[nt][0] = *reinterpret_cast<const bf16x8*>(&Kb_[ro + xorsw0]);
            kf[nt][1] = *reinterpret_cast<const bf16x8*>(&Kb_[ro + xorsw1]);
        }

        f32x4 sc[4];
        __builtin_amdgcn_s_setprio(1);
        #pragma unroll
        for (int nt = 0; nt < 4; ++nt) {
            f32x4 z = (f32x4){0.f, 0.f, 0.f, 0.f};
            z = __builtin_amdgcn_mfma_f32_16x16x32_bf16(kf[nt][0], qf[0], z, 0, 0, 0);
            z = __builtin_amdgcn_mfma_f32_16x16x32_bf16(kf[nt][1], qf[1], z, 0, 0, 0);
            sc[nt] = z;
        }
        __builtin_amdgcn_s_setprio(0);

        if (kc == nch - 1) {
            const int qg = q0 + l;
            #pragma unroll
            for (int nt = 0; nt < 4; ++nt)
                #pragma unroll
                for (int r = 0; r < 4; ++r)
                    if (k0 + nt * 16 + g * 4 + r > qg) sc[nt][r] = -INFINITY;
        }

        {
            float mc = fmaxf(fmaxf(vmax4(sc[0]), vmax4(sc[1])),
                             fmaxf(vmax4(sc[2]), vmax4(sc[3])));
            mc = fmaxf(mc, __shfl_xor(mc, 16, 64));
            mc = fmaxf(mc, __shfl_xor(mc, 32, 64));

            if (__any(mc > m_i + 8.f)) {              // defer-max rescale
                const float mn = fmaxf(m_i, mc);
                const float al = exp2f(m_i - mn);
                m_i = mn;
                l_i *= al;
                #pragma unroll
                for (int r = 0; r < 4; ++r) {
                    const float ar = __shfl(al, 4 * g + r, 64);
                    #pragma unroll
                    for (int dt = 0; dt < 4; ++dt) accO[dt][r] *= ar;
                }
            }

            float psum[4];
            #pragma unroll
            for (int nt = 0; nt < 4; ++nt) {
                #pragma unroll
                for (int r = 0; r < 4; ++r)
                    sc[nt][r] = exp2f(sc[nt][r] - m_i);
                psum[nt] = (sc[nt][0] + sc[nt][1]) + (sc[nt][2] + sc[nt][3]);
            }
            float rs = (psum[0] + psum[1]) + (psum[2] + psum[3]);
            rs += __shfl_xor(rs, 16, 64);
            rs += __shfl_xor(rs, 32, 64);
            l_i += rs;

            const int prow = w * 16 + l;
            #pragma unroll
            for (int nt = 0; nt < 4; ++nt)
                *reinterpret_cast<ushort4*>(
                    &Pl[prow * 64 + ((nt * 16 + 4 * g) ^ ((l & 7) << 3))]) =
                    pack4bf(sc[nt][0], sc[nt][1], sc[nt][2], sc[nt][3]);
        }

        bf16x8 vf[4][2];
        #pragma unroll
        for (int dt = 0; dt < 4; ++dt) {
            const int ro = (dt * 16 + l) * 64;
            vf[dt][0] = *reinterpret_cast<const bf16x8*>(&Vb_[ro + xorsw0]);
            vf[dt][1] = *reinterpret_cast<const bf16x8*>(&Vb_[ro + xorsw1]);
        }
        bf16x8 pf[2];
        const int prow = w * 16 + l;
        pf[0] = *reinterpret_cast<const bf16x8*>(&Pl[prow * 64 + ((8 * g) ^ ((l & 7) << 3))]);
        pf[1] = *reinterpret_cast<const bf16x8*>(&Pl[prow * 64 + ((32 + 8 * g) ^ ((l & 7) << 3))]);
        __builtin_amdgcn_s_setprio(1);
        #pragma unroll
        for (int dt = 0; dt < 4; ++dt) {
            accO[dt] = __builtin_amdgcn_mfma_f32_16x16x32_bf16(pf[0], vf[dt][0], accO[dt], 0, 0, 0);
            accO[dt] = __builtin_amdgcn_mfma_f32_16x16x32_bf16(pf[1], vf[dt][1], accO[dt], 0, 0, 0);
        }
        __builtin_amdgcn_s_setprio(0);
    };

    STAGE(0, 0);
    __syncthreads();

    int cur = 0;
    for (int kc = 0; kc < nch; ++kc) {
        if (kc + 1 < nch) STAGE(cur ^ 1, kc + 1);
        COMPUTE(cur, kc);
        __syncthreads();
        cur ^= 1;
    }

    // epilogue: normalize, emit attended bf16
    #pragma unroll
    for (int r = 0; r < 4; ++r) {
        const float lr = __shfl(l_i, 4 * g + r, 64);
        const float inv = 1.f / lr;
        const size_t row = (size_t)(b * SEQ + q0 + g * 4 + r) * DMODEL + h * 64;
        #pragma unroll
        for (int dt = 0; dt < 4; ++dt)
            ATh[row + dt * 16 + l] = f2bf(accO[dt][r] * inv);
    }
}

// ---------------- out GEMM: single-pass Ah·Bh, 128x64 tile, BK=64, fp32 out ----------------
__global__ __launch_bounds__(512) void gemm_o(const ushort* __restrict__ Ahg,
                                              const ushort* __restrict__ Bhg,
                                              float* __restrict__ C) {
    __shared__ ushort SH[12288];   // Ah 16KB | Bh 8KB
    ushort* const Ah = SH;
    ushort* const Bh = SH + 8192;

    const int t = threadIdx.x, lane = t & 63, w = t >> 6;
    const int l = lane & 15, g = lane >> 4;
    const int wm = w >> 1, wn = w & 1;
    const int bm = blockIdx.y * 128, bn = blockIdx.x * 64;

    f32x4 acc[2][2];
    #pragma unroll
    for (int mt = 0; mt < 2; ++mt)
        #pragma unroll
        for (int nt = 0; nt < 2; ++nt) acc[mt][nt] = (f32x4){0.f, 0.f, 0.f, 0.f};

    for (int kt = 0; kt < DMODEL; kt += 64) {
        __syncthreads();
        #pragma unroll
        for (int i = 0; i < 3; ++i) {
            const int sid = w * 3 + i;            // 0..23
            const ushort* src; ushort* dst; int rb, c;
            if (sid < 16) { src = Ahg; dst = Ah; rb = bm; c = sid; }
            else          { src = Bhg; dst = Bh; rb = bn; c = sid - 16; }
            const int row = c * 8 + (lane >> 3);
            const int sw = ((lane & 7) ^ (row & 7)) << 3;
            GLD16(src + (size_t)(rb + row) * DMODEL + kt + sw, dst + c * 512);
        }
        __syncthreads();

        bf16x8 ah[2][2], bhf[2][2];
        #pragma unroll
        for (int mt = 0; mt < 2; ++mt)
            #pragma unroll
            for (int s = 0; s < 2; ++s) {
                const int m = wm * 32 + mt * 16 + l;
                ah[mt][s] = *reinterpret_cast<const bf16x8*>(&Ah[m * 64 + (((g + 4 * s) ^ (m & 7)) << 3)]);
            }
        #pragma unroll
        for (int nt = 0; nt < 2; ++nt)
            #pragma unroll
            for (int s = 0; s < 2; ++s) {
                const int n = wn * 32 + nt * 16 + l;
                bhf[nt][s] = *reinterpret_cast<const bf16x8*>(&Bh[n * 64 + (((g + 4 * s) ^ (n & 7)) << 3)]);
            }
        __builtin_amdgcn_s_setprio(1);
        #pragma unroll
        for (int mt = 0; mt < 2; ++mt)
            #pragma unroll
            for (int nt = 0; nt < 2; ++nt)
                #pragma unroll
                for (int s = 0; s < 2; ++s)
                    acc[mt][nt] = __builtin_amdgcn_mfma_f32_16x16x32_bf16(ah[mt][s], bhf[nt][s], acc[mt][nt], 0, 0, 0);
        __builtin_amdgcn_s_setprio(0);
    }

    #pragma unroll
    for (int mt = 0; mt < 2; ++mt)
        #pragma unroll
        for (int nt = 0; nt < 2; ++nt)
            #pragma unroll
            for (int r = 0; r < 4; ++r) {
                const int row = bm + wm * 32 + mt * 16 + g * 4 + r;
                const int col = bn + wn * 32 + nt * 16 + l;
                C[(size_t)row * DMODEL + col] = acc[mt][nt][r];
            }
}

// ---------------- launch ----------------
extern "C" void kernel_launch(void* const* d_in, const int* in_sizes, int n_in,
                              void* d_out, int out_size, void* d_ws, size_t ws_size,
                              hipStream_t stream) {
    const float* x  = (const float*)d_in[0];
    const float* Wq = (const float*)d_in[1];
    const float* Wk = (const float*)d_in[2];
    const float* Wv = (const float*)d_in[3];
    const float* Wo = (const float*)d_in[4];
    float* out = (float*)d_out;

    char* ws = (char*)d_ws;
    const size_t MB = 1024 * 1024;
    ushort* xh  = (ushort*)(ws);              // 8 MB (aliased as ATh after QKV gemm)
    ushort* ath = xh;
    ushort* wtc = (ushort*)(ws + 16 * MB);    // 6 MB  [3072][1024]
    ushort* woh = (ushort*)(ws + 22 * MB);    // 2 MB
    ushort* Qb  = (ushort*)(ws + 26 * MB);    // 8 MB
    ushort* Kb  = (ushort*)(ws + 34 * MB);    // 8 MB
    ushort* Vtb = (ushort*)(ws + 42 * MB);    // 8 MB

    prep<<<dim3(16, 16, 5), 256, 0, stream>>>(x, Wq, Wk, Wv, Wo, wtc, woh, xh);

    gemm_qkv<<<dim3(24, 32), 256, 0, stream>>>(xh, wtc, Qb, Kb, Vtb);

    attn<<<dim3(32, 32), 256, 0, stream>>>(Qb, Kb, Vtb, ath);

    gemm_o<<<dim3(16, 32), 512, 0, stream>>>(ath, woh, out);
}